// Round 3
// baseline (439.546 us; speedup 1.0000x reference)
//
#include <hip/hip_runtime.h>
#include <hip/hip_bf16.h>

// Problem constants (match reference)
#define NN   50000   // N0+N1
#define NN0  30000
#define EE   400000
#define NB_SCAN ((NN + 1023) / 1024)   // 49
#define NB_E  ((EE + 255) / 256)       // 1563
#define NRT   3125                     // row tiles (16 rows each)
#define NGRP  ((NRT + 3) / 4)          // 782 row groups (64 rows)
#define NT0   1875                     // type-0 row tiles (30000/16, exact)

typedef unsigned short u16;
typedef unsigned int   u32;

typedef __attribute__((ext_vector_type(8))) __bf16 bf16x8;
typedef __attribute__((ext_vector_type(4))) float  f32x4;
typedef __attribute__((ext_vector_type(2))) float  f32x2;

// ---------- bf16 storage helpers (fp32 math everywhere) ----------
__device__ __forceinline__ float bf2f(u16 u){ return __uint_as_float(((u32)u)<<16); }
__device__ __forceinline__ float lo16(u32 u){ return __uint_as_float(u<<16); }
__device__ __forceinline__ float hi16(u32 u){ return __uint_as_float(u & 0xffff0000u); }
__device__ __forceinline__ u16 f2bf(float f){
  u32 x = __float_as_uint(f);
  x += 0x7fffu + ((x>>16)&1u);      // round-to-nearest-even
  return (u16)(x>>16);
}
__device__ __forceinline__ float elu_f(float x){ return x>0.f ? x : __expf(x)-1.f; }
__device__ __forceinline__ float lrelu(float x){ return x>0.f ? x : 0.2f*x; }
__device__ __forceinline__ bf16x8 ld_frag(const u16* p){
  uint4 v = *(const uint4*)p;
  return __builtin_bit_cast(bf16x8, v);
}
__device__ __forceinline__ bf16x8 cvt8(const float* p){   // 8 f32 -> bf16x8
  float4 u = ((const float4*)p)[0];
  float4 v = ((const float4*)p)[1];
  u32 w0 = (u32)f2bf(u.x) | ((u32)f2bf(u.y)<<16);
  u32 w1 = (u32)f2bf(u.z) | ((u32)f2bf(u.w)<<16);
  u32 w2 = (u32)f2bf(v.x) | ((u32)f2bf(v.y)<<16);
  u32 w3 = (u32)f2bf(v.z) | ((u32)f2bf(v.w)<<16);
  uint4 r{w0,w1,w2,w3};
  return __builtin_bit_cast(bf16x8, r);
}
// accumulate 8 bf16 cols (uint4) weighted by x into 4 f32x2 pairs via v_pk_fma_f32
__device__ __forceinline__ void acc8pk(f32x2* p, float& den, float x, uint4 f){
  den += x;
  f32x2 xx = {x, x};
  f32x2 t0 = {lo16(f.x), hi16(f.x)};
  f32x2 t1 = {lo16(f.y), hi16(f.y)};
  f32x2 t2 = {lo16(f.z), hi16(f.z)};
  f32x2 t3 = {lo16(f.w), hi16(f.w)};
  p[0] = __builtin_elementwise_fma(t0, xx, p[0]);
  p[1] = __builtin_elementwise_fma(t1, xx, p[1]);
  p[2] = __builtin_elementwise_fma(t2, xx, p[2]);
  p[3] = __builtin_elementwise_fma(t3, xx, p[3]);
}
// accumulate 2 bf16 cols (u32) into 4 head accumulators (pk_fma) + packed dens
__device__ __forceinline__ void acc2x4(f32x2* a, f32x2& d01, f32x2& d23, float4 x, u32 w){
  f32x2 v = {lo16(w), hi16(w)};
  f32x2 x0 = {x.x, x.x}, x1 = {x.y, x.y}, x2 = {x.z, x.z}, x3 = {x.w, x.w};
  a[0] = __builtin_elementwise_fma(v, x0, a[0]);
  a[1] = __builtin_elementwise_fma(v, x1, a[1]);
  a[2] = __builtin_elementwise_fma(v, x2, a[2]);
  a[3] = __builtin_elementwise_fma(v, x3, a[3]);
  f32x2 p01 = {x.x, x.y}, p23 = {x.z, x.w};
  d01 += p01; d23 += p23;
}

// ---------- prep (blocks 0..99) ∪ prep2 (blocks 100..131) ----------
// prep: zero counters + mixw softmax + all weight packing
// prep2: V2 = fc_w @ [W0*al | W0*ar] (128x16 per type) + bV
__global__ __launch_bounds__(256) void k_prepAll(
    const float* __restrict__ mix_w, float* __restrict__ wsoft,
    const float* __restrict__ W0, u16* __restrict__ W0p,
    const float* __restrict__ W1, u16* __restrict__ W1p,
    const float* __restrict__ W2, const float* __restrict__ res2, u16* __restrict__ W2p,
    const float* __restrict__ fcw0, const float* __restrict__ fcw1, u16* __restrict__ Fp,
    const float* __restrict__ al0, const float* __restrict__ ar0,
    const float* __restrict__ fcb0, const float* __restrict__ fcb1,
    u16* __restrict__ V2p, float* __restrict__ bV,
    int* __restrict__ zeros)
{
  __shared__ float V[64];
  if (blockIdx.x >= 100){
    // ---- prep2 part: 32 blocks ----
    int b = blockIdx.x - 100;
    int tt = b>>4, cl = b&15;
    int which = cl>>3, g = (cl>>2)&1, h = cl&3;
    int t = threadIdx.x;
    const float* sel = (which ? ar0 : al0) + (size_t)(g*4+h)*64;
    if (t < 64){
      const float* Wrow = W0 + (size_t)g*16384 + (size_t)t*256 + h*64;
      float s = 0.f;
      #pragma unroll 8
      for (int d=0; d<64; d++) s = fmaf(Wrow[d], sel[d], s);
      V[t] = s;
    }
    __syncthreads();
    if (t < 128){
      const float* fw = tt ? fcw1 : fcw0;   // 128 x 64
      float s = 0.f;
      #pragma unroll 8
      for (int d=0; d<64; d++) s = fmaf(fw[(size_t)t*64 + d], V[d], s);
      int kb = t>>5, q = (t>>3)&3, j = t&7;
      V2p[(size_t)tt*2048 + ((size_t)kb*64 + q*16 + cl)*8 + j] = f2bf(s);
      if (t == 0){
        const float* fbp = tt ? fcb1 : fcb0;
        float sb = 0.f;
        #pragma unroll 8
        for (int d=0; d<64; d++) sb = fmaf(fbp[d], V[d], sb);
        bV[tt*16 + cl] = sb;
      }
    }
    return;
  }
  // ---- prep part: 100 blocks ----
  int t = blockIdx.x*256 + threadIdx.x;
  for (int z = t; z < 4*NN; z += 100*256) zeros[z] = 0;
  if (t < 6){
    float a0 = mix_w[t*2+0], a1 = mix_w[t*2+1];
    float mx = fmaxf(a0,a1);
    float e0 = __expf(a0-mx), e1 = __expf(a1-mx);
    wsoft[t*2+0] = e0/(e0+e1); wsoft[t*2+1] = e1/(e0+e1);
  }
  if (t < 4096){                    // W0: per graph 2048 frags, KB=2, NCOL=256
    int gg = t>>11, fi = t&2047;
    int lane = fi&63, kb = (fi>>6)&1, ct = fi>>7;
    int q = lane>>4, c = lane&15;
    const float* src = W0 + (size_t)gg*16384;
    u16* o = W0p + (size_t)gg*16384 + (size_t)fi*8;
    #pragma unroll
    for (int j=0;j<8;j++) o[j] = f2bf(src[(size_t)(kb*32+q*8+j)*256 + ct*16 + c]);
  } else if (t < 20480){            // W1: per graph 8192 frags, KB=8, NCOL=256
    int u = t - 4096;
    int gg = u>>13, fi = u&8191;
    int lane = fi&63, kb = (fi>>6)&7, ct = fi>>9;
    int q = lane>>4, c = lane&15;
    const float* src = W1 + (size_t)gg*65536;
    u16* o = W1p + (size_t)gg*65536 + (size_t)fi*8;
    #pragma unroll
    for (int j=0;j<8;j++) o[j] = f2bf(src[(size_t)(kb*32+q*8+j)*256 + ct*16 + c]);
  } else if (t < 22528){            // W2cat: 2048 frags, KB=8, NCOL=64
    int fi = t - 20480;
    int lane = fi&63, kb = (fi>>6)&7, ct = fi>>9;
    int q = lane>>4, c = lane&15;
    int cl = ct*16 + c;
    int i = cl>>5, which = (cl>>4)&1;
    const float* src = which ? res2 : W2;
    u16* o = W2p + (size_t)fi*8;
    #pragma unroll
    for (int j=0;j<8;j++) o[j] = f2bf(src[(size_t)i*4096 + (size_t)(kb*32+q*8+j)*16 + (cl&15)]);
  } else if (t < 24576){            // fc_w: per type 1024 frags, KB=4, NCOL=64
    int u = t - 22528;
    int tt = u>>10, fi = u&1023;
    int lane = fi&63, kb = (fi>>6)&3, ct = fi>>8;
    int q = lane>>4, c = lane&15;
    const float* src = tt ? fcw1 : fcw0;
    u16* o = Fp + (size_t)tt*8192 + (size_t)fi*8;
    #pragma unroll
    for (int j=0;j<8;j++) o[j] = f2bf(src[(size_t)(kb*32+q*8+j)*64 + ct*16 + c]);
  }
}

// ---------- fused: input projection MFMA (blocks 0..NGRP-1) ∪ edge count ------
// inproj: h0 = feats @ fc_w + fc_b;  el/er = feats @ V2 + bV
// count : cnt2[g][dst] += 1  (blocks NGRP .. NGRP+2*NB_E-1)
__global__ __launch_bounds__(256) void k_inpcnt(
    const float* __restrict__ f0, const float* __restrict__ f1,
    const u16* __restrict__ Fp, const float* __restrict__ fb0, const float* __restrict__ fb1,
    const u16* __restrict__ V2p, const float* __restrict__ bV,
    u16* __restrict__ h0, float* __restrict__ elA, float* __restrict__ erA,
    const int* __restrict__ d0, const int* __restrict__ d1, int* __restrict__ cnt2)
{
  if (blockIdx.x >= NGRP){
    int u = blockIdx.x - NGRP;
    int g = u / NB_E;
    int t = (u % NB_E)*256 + threadIdx.x;
    if (t < EE) atomicAdd(&cnt2[g*NN + (g ? d1[t] : d0[t])], 1);
    return;
  }
  int wv = threadIdx.x>>6, ln = threadIdx.x&63;
  int ti = blockIdx.x*4 + wv;
  if (ti >= NRT) return;
  int q = ln>>4, c = ln&15;
  int type = (ti < NT0) ? 0 : 1;
  const float* F = type ? f1 : f0;
  int rbase = type ? (ti*16 - NN0) : ti*16;
  const u16* Bg = Fp + (size_t)type*8192;
  const u16* Vg = V2p + (size_t)type*2048;
  const float* bb = type ? fb1 : fb0;
  f32x4 acc[4] = {};
  f32x4 accE = {};
  const float* Ap = F + (size_t)(rbase + c)*128;
  #pragma unroll
  for (int kb=0; kb<4; kb++){
    bf16x8 a = cvt8(Ap + kb*32 + q*8);
    #pragma unroll
    for (int ct=0; ct<4; ct++){
      bf16x8 b = ld_frag(Bg + ((size_t)(ct*4+kb)*64 + ln)*8);
      acc[ct] = __builtin_amdgcn_mfma_f32_16x16x32_bf16(a, b, acc[ct], 0,0,0);
    }
    bf16x8 bv_ = ld_frag(Vg + ((size_t)kb*64 + ln)*8);
    accE = __builtin_amdgcn_mfma_f32_16x16x32_bf16(a, bv_, accE, 0,0,0);
  }
  #pragma unroll
  for (int ct=0; ct<4; ct++){
    float bvs = bb[ct*16+c];
    #pragma unroll
    for (int j=0;j<4;j++){
      int row = ti*16 + q*4 + j;
      h0[(size_t)row*64 + ct*16 + c] = f2bf(acc[ct][j] + bvs);
    }
  }
  int which = c>>3, gg = (c>>2)&1, hh = c&3;
  float bVv = bV[type*16 + c];
  float* dst = (which ? erA : elA) + (size_t)gg*NN*4;
  #pragma unroll
  for (int j=0;j<4;j++){
    int row = ti*16 + q*4 + j;
    dst[row*4 + hh] = accE[j] + bVv;
  }
}

// ================= CSR build (both graphs, rebuilt every launch) ===============
__global__ __launch_bounds__(1024) void k_scan1(const int* __restrict__ cnt2,
                                                int* __restrict__ row2, int* __restrict__ bsum){
  __shared__ int wsum[16];
  int g = blockIdx.y;
  int lane = threadIdx.x & 63, wid = threadIdx.x >> 6;
  int i = blockIdx.x*1024 + threadIdx.x;
  int v = (i < NN) ? cnt2[g*NN + i] : 0;
  int x = v;
  #pragma unroll
  for (int off = 1; off < 64; off <<= 1){
    int y = __shfl_up(x, off, 64);
    if (lane >= off) x += y;
  }
  if (lane == 63) wsum[wid] = x;
  __syncthreads();
  if (wid == 0 && lane < 16){
    int s = wsum[lane];
    #pragma unroll
    for (int off = 1; off < 16; off <<= 1){
      int y = __shfl_up(s, off, 16);
      if (lane >= off) s += y;
    }
    wsum[lane] = s;
  }
  __syncthreads();
  int incl = x + (wid ? wsum[wid-1] : 0);
  if (i < NN) row2[(size_t)g*(NN+1) + i] = incl - v;
  if (threadIdx.x == 1023) bsum[g*NB_SCAN + blockIdx.x] = incl;
}

__global__ __launch_bounds__(1024) void k_scan3(int* __restrict__ row2,
                                                const int* __restrict__ bsum){
  __shared__ int base;
  int g = blockIdx.y;
  if (threadIdx.x < 64){
    int lane = threadIdx.x;
    int v = (lane < (int)blockIdx.x) ? bsum[g*NB_SCAN + lane] : 0;
    #pragma unroll
    for (int off = 32; off; off >>= 1) v += __shfl_xor(v, off, 64);
    if (lane == 0) base = v;
  }
  __syncthreads();
  int i = blockIdx.x*1024 + threadIdx.x;
  if (i < NN) row2[(size_t)g*(NN+1) + i] += base;
  if (blockIdx.x == 0 && threadIdx.x == 0) row2[(size_t)g*(NN+1) + NN] = EE;
}

__global__ void k_scatter2(const int* __restrict__ s0, const int* __restrict__ d0,
                           const int* __restrict__ s1, const int* __restrict__ d1,
                           const int* __restrict__ row2, int* __restrict__ fill2,
                           u16* __restrict__ col2, u16* __restrict__ dstOf){
  int t = blockIdx.x*256 + threadIdx.x;
  int g = blockIdx.y;
  if (t >= EE) return;
  int d = g ? d1[t] : d0[t];
  int s = g ? s1[t] : s0[t];
  int pos = atomicAdd(&fill2[g*NN + d], 1);
  size_t slot = (size_t)g*EE + row2[(size_t)g*(NN+1) + d] + pos;
  col2[slot]  = (u16)s;
  dstOf[slot] = (u16)d;
}

// ---------- alpha precompute (H=4), edge-parallel ----------
__global__ void k_alpha4(const u16* __restrict__ col2, const u16* __restrict__ dstOf,
                         const float* __restrict__ el, const float* __restrict__ er,
                         size_t elStride, float* __restrict__ xbuf){
  int t = blockIdx.x*256 + threadIdx.x;
  int g = blockIdx.y;
  if (t >= EE) return;
  size_t slot = (size_t)g*EE + t;
  int s = col2[slot], d = dstOf[slot];
  const float* elg = el + (size_t)g*elStride;
  const float* erg = er + (size_t)g*elStride;
  float4 e4 = ((const float4*)elg)[s];
  float4 r4 = ((const float4*)erg)[d];
  float4 x;
  x.x = __expf(lrelu(e4.x + r4.x));
  x.y = __expf(lrelu(e4.y + r4.y));
  x.z = __expf(lrelu(e4.z + r4.z));
  x.w = __expf(lrelu(e4.w + r4.w));
  ((float4*)xbuf)[slot] = x;
}

// ---------- layer-0 aggregation: gather h0 (64 cols), BOTH graphs ---------
// v4: 2-deep software pipeline — iteration t issues index/x loads AND feature
// gathers for t+1 before consuming t's gathers (counted-vmcnt overlap).
__global__ __launch_bounds__(128) void k_agg0(
    const int* __restrict__ row2, const u16* __restrict__ col2,
    const float* __restrict__ xbuf, const u16* __restrict__ h0,
    u16* __restrict__ aggB, size_t aggStride)
{
  int wv = threadIdx.x>>6, ln = threadIdx.x&63;
  int n = blockIdx.x*2 + wv;
  int half = ln>>5, l32 = ln&31;
  const int* rw0 = row2;
  const int* rw1 = row2 + (NN+1);
  const u16* cl0 = col2;
  const u16* cl1 = col2 + EE;
  const float4* xb0 = (const float4*)xbuf;
  const float4* xb1 = xb0 + EE;
  const u32* hp = (const u32*)h0;          // 32 u32 per row
  int b0_ = rw0[n], e0_ = rw0[n+1];
  int b1_ = rw1[n], e1_ = rw1[n+1];
  int n0 = e0_-b0_, n1 = e1_-b1_;
  int mx = n0>n1 ? n0 : n1;
  int iters = (mx+3)>>2;
  f32x2 aA[4] = {}; f32x2 aB[4] = {};
  f32x2 dA01 = {}, dA23 = {}, dB01 = {}, dB23 = {};
  float4 z = {0.f,0.f,0.f,0.f};
  int k0 = b0_+half, k1 = b1_+half;
  // prologue: stage t=0
  bool v00=k0<e0_, v01=k0+2<e0_, v10=k1<e1_, v11=k1+2<e1_;
  int ci0=v00?k0:0, ci1=v01?k0+2:0, cj0=v10?k1:0, cj1=v11?k1+2:0;
  int sA0=cl0[ci0], sA1=cl0[ci1], sB0=cl1[cj0], sB1=cl1[cj1];
  float4 xA0=v00?xb0[ci0]:z, xA1=v01?xb0[ci1]:z;
  float4 xB0=v10?xb1[cj0]:z, xB1=v11?xb1[cj1]:z;
  u32 wA0=hp[(size_t)sA0*32+l32], wA1=hp[(size_t)sA1*32+l32];
  u32 wB0=hp[(size_t)sB0*32+l32], wB1=hp[(size_t)sB1*32+l32];
  for (int t=0; t<iters; ++t){
    // prefetch t+1 (clamped; last iter loads slot 0 harmlessly)
    int nk0=k0+4, nk1=k1+4;
    bool w00=nk0<e0_, w01=nk0+2<e0_, w10=nk1<e1_, w11=nk1+2<e1_;
    int di0=w00?nk0:0, di1=w01?nk0+2:0, dj0=w10?nk1:0, dj1=w11?nk1+2:0;
    int tA0=cl0[di0], tA1=cl0[di1], tB0=cl1[dj0], tB1=cl1[dj1];
    float4 yA0=w00?xb0[di0]:z, yA1=w01?xb0[di1]:z;
    float4 yB0=w10?xb1[dj0]:z, yB1=w11?xb1[dj1]:z;
    u32 gA0=hp[(size_t)tA0*32+l32], gA1=hp[(size_t)tA1*32+l32];
    u32 gB0=hp[(size_t)tB0*32+l32], gB1=hp[(size_t)tB1*32+l32];
    // consume t (gathers issued previous iteration)
    acc2x4(aA, dA01, dA23, xA0, wA0);
    acc2x4(aA, dA01, dA23, xA1, wA1);
    acc2x4(aB, dB01, dB23, xB0, wB0);
    acc2x4(aB, dB01, dB23, xB1, wB1);
    // rotate
    xA0=yA0; xA1=yA1; xB0=yB0; xB1=yB1;
    wA0=gA0; wA1=gA1; wB0=gB0; wB1=gB1;
    k0=nk0; k1=nk1;
  }
  // cross-half reduction
  #pragma unroll
  for (int u=0;u<4;u++){
    aA[u].x += __shfl_xor(aA[u].x,32,64); aA[u].y += __shfl_xor(aA[u].y,32,64);
    aB[u].x += __shfl_xor(aB[u].x,32,64); aB[u].y += __shfl_xor(aB[u].y,32,64);
  }
  dA01.x += __shfl_xor(dA01.x,32,64); dA01.y += __shfl_xor(dA01.y,32,64);
  dA23.x += __shfl_xor(dA23.x,32,64); dA23.y += __shfl_xor(dA23.y,32,64);
  dB01.x += __shfl_xor(dB01.x,32,64); dB01.y += __shfl_xor(dB01.y,32,64);
  dB23.x += __shfl_xor(dB23.x,32,64); dB23.y += __shfl_xor(dB23.y,32,64);
  if (!half){
    bool hg0 = e0_ > b0_, hg1 = e1_ > b1_;
    float iA[4] = { hg0?1.f/dA01.x:0.f, hg0?1.f/dA01.y:0.f, hg0?1.f/dA23.x:0.f, hg0?1.f/dA23.y:0.f };
    float iB[4] = { hg1?1.f/dB01.x:0.f, hg1?1.f/dB01.y:0.f, hg1?1.f/dB23.x:0.f, hg1?1.f/dB23.y:0.f };
    u32* og0 = (u32*)(aggB + (size_t)n*256);
    u32* og1 = (u32*)(aggB + aggStride + (size_t)n*256);
    #pragma unroll
    for (int h=0;h<4;h++){
      u32 w0 = (u32)f2bf(aA[h].x*iA[h]) | ((u32)f2bf(aA[h].y*iA[h])<<16);
      og0[h*32 + l32] = w0;
      u32 w1 = (u32)f2bf(aB[h].x*iB[h]) | ((u32)f2bf(aB[h].y*iB[h])<<16);
      og1[h*32 + l32] = w1;
    }
  }
}

// ---------- layer-0 head GEMM: ELU(agg@W0_blockdiag + b) mixed -> h1 ----------
__global__ __launch_bounds__(256) void k_head0(
    const u16* __restrict__ aggB, size_t aggStride,
    const u16* __restrict__ W0p, const float* __restrict__ b0,
    const float* __restrict__ wsoft, u16* __restrict__ h1)
{
  int wv = threadIdx.x>>6, ln = threadIdx.x&63;
  int ti = blockIdx.x*4 + wv;
  if (ti >= NRT) return;
  int q = ln>>4, c = ln&15;
  int type = (ti < NT0) ? 0 : 1;
  float wg0 = wsoft[type*6 + 0];
  float wg1 = wsoft[type*6 + 1];
  for (int h=0; h<4; h++){
    f32x4 acc[2][4] = {};
    #pragma unroll
    for (int g=0; g<2; g++){
      const u16* Ap = aggB + (size_t)g*aggStride + (size_t)(ti*16 + c)*256 + h*64 + q*8;
      const u16* Bg = W0p + (size_t)g*16384;
      #pragma unroll
      for (int kb=0; kb<2; kb++){
        bf16x8 a = ld_frag(Ap + kb*32);
        #pragma unroll
        for (int ct=0; ct<4; ct++){
          int ctg = h*4 + ct;
          bf16x8 b = ld_frag(Bg + ((size_t)(ctg*2 + kb)*64 + ln)*8);
          acc[g][ct] = __builtin_amdgcn_mfma_f32_16x16x32_bf16(a, b, acc[g][ct], 0,0,0);
        }
      }
    }
    #pragma unroll
    for (int ct=0; ct<4; ct++){
      int colg = h*64 + ct*16 + c;
      float bb0 = b0[colg], bb1 = b0[256 + colg];
      #pragma unroll
      for (int j=0;j<4;j++){
        int row = ti*16 + q*4 + j;
        float o = wg0*elu_f(acc[0][ct][j] + bb0) + wg1*elu_f(acc[1][ct][j] + bb1);
        h1[(size_t)row*256 + colg] = f2bf(o);
      }
    }
  }
}

// ---------- MFMA GEMM, 4 row-tiles x 4 col-tiles per wave (layer 1) ------------
template<int K>
__global__ __launch_bounds__(256) void k_gemm4(
    const u16* __restrict__ A,
    const u16* __restrict__ Bp, size_t bpStride,
    const float* __restrict__ al, const float* __restrict__ ar, int alStride,
    u16* __restrict__ feat, size_t featStride,
    float* __restrict__ el, float* __restrict__ er, size_t elStride)
{
  constexpr int KB = K/32;
  int wv = threadIdx.x>>6, ln = threadIdx.x&63;
  int bid = blockIdx.x;
  int g = bid / NGRP, grp = bid % NGRP;
  int split = wv, q = ln>>4, c = ln&15;
  const u16* Bpg = Bp + (size_t)g*bpStride;
  const float* alg = al + (size_t)g*alStride;
  const float* arg = ar + (size_t)g*alStride;
  u16* featg = feat + (size_t)g*featStride;
  float* elg = el + (size_t)g*elStride;
  float* erg = er + (size_t)g*elStride;

  f32x4 acc[4][4] = {};
  int  tbase = grp*4;
  bool valid[4];
  const u16* Ap[4];
  #pragma unroll
  for (int rt=0; rt<4; rt++){
    int ti = tbase + rt;
    valid[rt] = (ti < NRT);
    if (!valid[rt]) ti = NRT-1;
    Ap[rt] = A + (size_t)(ti*16 + c)*K + q*8;
  }
  const u16* Bbase = Bpg + ((size_t)(split*4)*KB*64 + ln)*8;

  #pragma unroll 2
  for (int kb=0; kb<KB; kb++){
    bf16x8 b[4], a[4];
    #pragma unroll
    for (int ct=0; ct<4; ct++) b[ct] = ld_frag(Bbase + (size_t)(ct*KB + kb)*64*8);
    #pragma unroll
    for (int rt=0; rt<4; rt++) a[rt] = ld_frag(Ap[rt] + kb*32);
    #pragma unroll
    for (int rt=0; rt<4; rt++)
      #pragma unroll
      for (int ct=0; ct<4; ct++)
        acc[rt][ct] = __builtin_amdgcn_mfma_f32_16x16x32_bf16(a[rt], b[ct], acc[rt][ct], 0,0,0);
  }

  float alv[4], arv[4];
  #pragma unroll
  for (int ct=0;ct<4;ct++){
    int cg = (split*4+ct)*16 + c;
    alv[ct] = alg[cg]; arv[ct] = arg[cg];
  }
  #pragma unroll
  for (int rt=0; rt<4; rt++){
    if (!valid[rt]) continue;
    int row0 = (tbase+rt)*16;
    #pragma unroll
    for (int j=0;j<4;j++){
      float ep=0.f, rp=0.f;
      #pragma unroll
      for (int ct=0;ct<4;ct++){ ep += acc[rt][ct][j]*alv[ct]; rp += acc[rt][ct][j]*arv[ct]; }
      #pragma unroll
      for (int off=8; off; off>>=1){ ep += __shfl_xor(ep,off,16); rp += __shfl_xor(rp,off,16); }
      int row = row0 + q*4 + j;
      if (c==0){ elg[row*4+split]=ep; erg[row*4+split]=rp; }
      #pragma unroll
      for (int ct=0;ct<4;ct++)
        featg[(size_t)row*256 + (split*4+ct)*16 + c] = f2bf(acc[rt][ct][j]);
    }
  }
}

// ---------- fused dual-graph gather aggregation (256 cols, H=4), layer 1 -------
// v4: 2-deep software pipeline on top of v3's half-wave split + pk_fma.
template<int RES>
__global__ __launch_bounds__(128) void k_aggNF(
    const int* __restrict__ row2, const u16* __restrict__ col2,
    const float* __restrict__ xbuf,
    const u16* __restrict__ feat, size_t featStride,
    const u16* __restrict__ hres, const float* __restrict__ bias,
    const float* __restrict__ wsoft, int l,
    u16* __restrict__ hout)
{
  int wv = threadIdx.x>>6, ln = threadIdx.x&63;
  int n = blockIdx.x*2 + wv;
  int half = ln>>5, l32 = ln&31;
  int hh = l32>>3;                       // head of this lane's 8 cols
  int type = (n<NN0)?0:1;
  const int* rw0 = row2;
  const int* rw1 = row2 + (NN+1);
  const u16* cl0 = col2;
  const u16* cl1 = col2 + EE;
  const float* x0p = xbuf;
  const float* x1p = xbuf + (size_t)EE*4;
  const uint4* fp0 = (const uint4*)feat;                  // row = 32 uint4
  const uint4* fp1 = (const uint4*)(feat + featStride);
  int b0_ = rw0[n], e0_ = rw0[n+1];
  int b1_ = rw1[n], e1_ = rw1[n+1];
  int n0 = e0_-b0_, n1 = e1_-b1_;
  int mx = n0>n1 ? n0 : n1;
  int iters = (mx+3)>>2;
  f32x2 pA[4] = {}; f32x2 pB[4] = {};
  float denA = 0.f, denB = 0.f;
  int k0 = b0_+half, k1 = b1_+half;
  // prologue: stage t=0
  bool v00=k0<e0_, v01=k0+2<e0_, v10=k1<e1_, v11=k1+2<e1_;
  int ci0=v00?k0:0, ci1=v01?k0+2:0, cj0=v10?k1:0, cj1=v11?k1+2:0;
  int sA0=cl0[ci0], sA1=cl0[ci1], sB0=cl1[cj0], sB1=cl1[cj1];
  float xA0=v00?x0p[(size_t)ci0*4+hh]:0.f;
  float xA1=v01?x0p[(size_t)ci1*4+hh]:0.f;
  float xB0=v10?x1p[(size_t)cj0*4+hh]:0.f;
  float xB1=v11?x1p[(size_t)cj1*4+hh]:0.f;
  uint4 fA0=fp0[(size_t)sA0*32+l32];
  uint4 fA1=fp0[(size_t)sA1*32+l32];
  uint4 fB0=fp1[(size_t)sB0*32+l32];
  uint4 fB1=fp1[(size_t)sB1*32+l32];
  for (int t=0; t<iters; ++t){
    // prefetch t+1 (clamped; last iter loads slot 0 harmlessly)
    int nk0=k0+4, nk1=k1+4;
    bool w00=nk0<e0_, w01=nk0+2<e0_, w10=nk1<e1_, w11=nk1+2<e1_;
    int di0=w00?nk0:0, di1=w01?nk0+2:0, dj0=w10?nk1:0, dj1=w11?nk1+2:0;
    int tA0=cl0[di0], tA1=cl0[di1], tB0=cl1[dj0], tB1=cl1[dj1];
    float yA0=w00?x0p[(size_t)di0*4+hh]:0.f;
    float yA1=w01?x0p[(size_t)di1*4+hh]:0.f;
    float yB0=w10?x1p[(size_t)dj0*4+hh]:0.f;
    float yB1=w11?x1p[(size_t)dj1*4+hh]:0.f;
    uint4 gA0=fp0[(size_t)tA0*32+l32];
    uint4 gA1=fp0[(size_t)tA1*32+l32];
    uint4 gB0=fp1[(size_t)tB0*32+l32];
    uint4 gB1=fp1[(size_t)tB1*32+l32];
    // consume t (gathers issued previous iteration)
    acc8pk(pA, denA, xA0, fA0);
    acc8pk(pA, denA, xA1, fA1);
    acc8pk(pB, denB, xB0, fB0);
    acc8pk(pB, denB, xB1, fB1);
    // rotate
    xA0=yA0; xA1=yA1; xB0=yB0; xB1=yB1;
    fA0=gA0; fA1=gA1; fB0=gB0; fB1=gB1;
    k0=nk0; k1=nk1;
  }
  // cross-half reduction (lane i and i^32 hold same cols, disjoint edges)
  #pragma unroll
  for (int u=0;u<4;u++){
    pA[u].x += __shfl_xor(pA[u].x,32,64); pA[u].y += __shfl_xor(pA[u].y,32,64);
    pB[u].x += __shfl_xor(pB[u].x,32,64); pB[u].y += __shfl_xor(pB[u].y,32,64);
  }
  denA += __shfl_xor(denA,32,64);
  denB += __shfl_xor(denB,32,64);
  if (!half){
    float accA[8], accB[8];
    #pragma unroll
    for (int u=0;u<4;u++){
      accA[2*u]=pA[u].x; accA[2*u+1]=pA[u].y;
      accB[2*u]=pB[u].x; accB[2*u+1]=pB[u].y;
    }
    float inv0 = (e0_>b0_) ? 1.0f/denA : 0.f;
    float inv1 = (e1_>b1_) ? 1.0f/denB : 0.f;
    const float4* bp0 = (const float4*)bias;
    const float4* bp1 = (const float4*)(bias + 256);
    float4 bva = bp0[l32*2], bvb = bp0[l32*2+1];
    float4 bwa = bp1[l32*2], bwb = bp1[l32*2+1];
    float bb0[8] = {bva.x,bva.y,bva.z,bva.w,bvb.x,bvb.y,bvb.z,bvb.w};
    float bb1[8] = {bwa.x,bwa.y,bwa.z,bwa.w,bwb.x,bwb.y,bwb.z,bwb.w};
    float w0 = wsoft[type*6 + l*2 + 0];
    float w1 = wsoft[type*6 + l*2 + 1];
    float r[8] = {0.f,0.f,0.f,0.f,0.f,0.f,0.f,0.f};
    if (RES){
      uint4 rr = ((const uint4*)hres)[(size_t)n*32 + l32];
      r[0]=lo16(rr.x); r[1]=hi16(rr.x); r[2]=lo16(rr.y); r[3]=hi16(rr.y);
      r[4]=lo16(rr.z); r[5]=hi16(rr.z); r[6]=lo16(rr.w); r[7]=hi16(rr.w);
    }
    u16 ov[8];
    #pragma unroll
    for (int j=0;j<8;j++){
      float c = accA[j]*inv0 + bb0[j] + r[j];
      float e = accB[j]*inv1 + bb1[j] + r[j];
      ov[j] = f2bf(w0*elu_f(c) + w1*elu_f(e));
    }
    uint4 o;
    o.x = (u32)ov[0] | ((u32)ov[1]<<16);
    o.y = (u32)ov[2] | ((u32)ov[3]<<16);
    o.z = (u32)ov[4] | ((u32)ov[5]<<16);
    o.w = (u32)ov[6] | ((u32)ov[7]<<16);
    ((uint4*)hout)[(size_t)n*32 + l32] = o;
  }
}

// ---------- layer-2 MFMA: A(N,256) @ [W2_0|res2_0|W2_1|res2_1](256,64) ----------
__global__ __launch_bounds__(256) void k_gemm2(
    const u16* __restrict__ A, const u16* __restrict__ Bp,
    const float* __restrict__ al2, const float* __restrict__ ar2,
    u16* __restrict__ feat16, float* __restrict__ resb,
    float* __restrict__ el2, float* __restrict__ er2)
{
  int wv = threadIdx.x>>6, ln = threadIdx.x&63;
  int wt = blockIdx.x*4 + wv;
  if (wt >= NRT) return;
  int row0 = wt*16;
  int q = ln>>4, c = ln&15;
  f32x4 acc[4] = {};
  const u16* Ap = A + (size_t)(row0 + c)*256 + q*8;
  #pragma unroll
  for (int kb=0; kb<8; kb++){
    bf16x8 a = ld_frag(Ap + kb*32);
    #pragma unroll
    for (int t=0;t<4;t++){
      bf16x8 b = ld_frag(Bp + ((size_t)(t*8 + kb)*64 + ln)*8);
      acc[t] = __builtin_amdgcn_mfma_f32_16x16x32_bf16(a, b, acc[t], 0,0,0);
    }
  }
  #pragma unroll
  for (int i=0;i<2;i++){
    float alv = al2[i*16+c], arv = ar2[i*16+c];
    #pragma unroll
    for (int j=0;j<4;j++){
      float ep = acc[2*i][j]*alv, rp = acc[2*i][j]*arv;
      #pragma unroll
      for (int off=8; off; off>>=1){ ep += __shfl_xor(ep,off,16); rp += __shfl_xor(rp,off,16); }
      if (c==0){
        int row = row0 + q*4 + j;
        el2[(size_t)i*NN + row] = ep; er2[(size_t)i*NN + row] = rp;
      }
    }
    #pragma unroll
    for (int j=0;j<4;j++){
      int row = row0 + q*4 + j;
      feat16[(size_t)i*NN*16 + (size_t)row*16 + c] = f2bf(acc[2*i][j]);
      resb  [(size_t)i*NN*16 + (size_t)row*16 + c] = acc[2*i+1][j];
    }
  }
}

// ---------- layer-2 dual-graph aggregation + inline alpha + final mix ----------
__global__ __launch_bounds__(256) void k_agg2D(
    const int* __restrict__ row2, const u16* __restrict__ col2,
    const float* __restrict__ el2, const float* __restrict__ er2,
    const u16* __restrict__ feat16, const float* __restrict__ resb,
    const float* __restrict__ b2, const float* __restrict__ wsoft,
    float* __restrict__ out)
{
  int t = threadIdx.x;
  int nl = t>>4, j = t&15;
  int n = blockIdx.x*16 + nl;
  int type = (n<NN0)?0:1;
  float o = 0.f;
  #pragma unroll
  for (int i=0;i<2;i++){
    const int* rw = row2 + (size_t)i*(NN+1);
    const u16* cl = col2 + (size_t)i*EE;
    const float* elg = el2 + (size_t)i*NN;
    float ern = er2[(size_t)i*NN + n];
    const u16* f = feat16 + (size_t)i*NN*16;
    int beg = rw[n], end = rw[n+1];
    float den = 0.f, acc = 0.f;
    int k = beg;
    for (; k+4<=end; k+=4){
      int s0=cl[k], s1=cl[k+1], s2=cl[k+2], s3=cl[k+3];
      float x0 = __expf(lrelu(elg[s0] + ern));
      float x1 = __expf(lrelu(elg[s1] + ern));
      float x2 = __expf(lrelu(elg[s2] + ern));
      float x3 = __expf(lrelu(elg[s3] + ern));
      float v0 = bf2f(f[(size_t)s0*16 + j]);
      float v1 = bf2f(f[(size_t)s1*16 + j]);
      float v2 = bf2f(f[(size_t)s2*16 + j]);
      float v3 = bf2f(f[(size_t)s3*16 + j]);
      den += (x0+x1) + (x2+x3);
      acc += x0*v0 + x1*v1 + x2*v2 + x3*v3;
    }
    for (; k<end; k++){
      int s = cl[k];
      float x = __expf(lrelu(elg[s] + ern));
      den += x;
      acc = fmaf(x, bf2f(f[(size_t)s*16 + j]), acc);
    }
    float inv = (end>beg) ? 1.0f/den : 0.f;
    float oi = acc*inv + b2[i*16+j] + resb[(size_t)i*NN*16 + (size_t)n*16 + j];
    o += oi * wsoft[type*6 + 4 + i];
  }
  out[(size_t)n*16 + j] = o;
}

extern "C" void kernel_launch(void* const* d_in, const int* in_sizes, int n_in,
                              void* d_out, int out_size, void* d_ws, size_t ws_size,
                              hipStream_t stream)
{
  const float* features0 = (const float*)d_in[0];
  const float* features1 = (const float*)d_in[1];
  const float* fc_w0 = (const float*)d_in[2];
  const float* fc_b0 = (const float*)d_in[3];
  const float* fc_w1 = (const float*)d_in[4];
  const float* fc_b1 = (const float*)d_in[5];
  const float* mix_w = (const float*)d_in[6];
  const float* W0  = (const float*)d_in[7];
  const float* al0 = (const float*)d_in[8];
  const float* ar0 = (const float*)d_in[9];
  const float* b0  = (const float*)d_in[10];
  const float* W1  = (const float*)d_in[11];
  const float* al1 = (const float*)d_in[12];
  const float* ar1 = (const float*)d_in[13];
  const float* b1  = (const float*)d_in[14];
  const float* W2  = (const float*)d_in[15];
  const float* al2 = (const float*)d_in[16];
  const float* ar2 = (const float*)d_in[17];
  const float* b2  = (const float*)d_in[18];
  const float* res2= (const float*)d_in[19];
  const int* src[2] = {(const int*)d_in[20], (const int*)d_in[22]};
  const int* dst[2] = {(const int*)d_in[21], (const int*)d_in[23]};
  (void)in_sizes; (void)n_in; (void)out_size; (void)ws_size;

  char* ws = (char*)d_ws;
  size_t off = 0;
  auto alloc = [&](size_t bytes)->char*{
    char* p = ws + off; off += (bytes + 255) & ~(size_t)255; return p;
  };
  float* wsoft = (float*)alloc(64*4);
  u16*   W0p   = (u16*)  alloc((size_t)2*64*256*2);
  u16*   W1p   = (u16*)  alloc((size_t)2*256*256*2);
  u16*   W2p   = (u16*)  alloc((size_t)256*64*2);
  u16*   Fp    = (u16*)  alloc((size_t)2*128*64*2);
  u16*   V2p   = (u16*)  alloc((size_t)2*128*16*2);
  float* bV    = (float*)alloc((size_t)32*4);
  int*   row2  = (int*)  alloc((size_t)2*(NN+1)*4);
  u16*   col2  = (u16*)  alloc((size_t)2*EE*2);
  u16*   dstOf = (u16*)  alloc((size_t)2*EE*2);
  int*   zeros = (int*)  alloc((size_t)4*NN*4);       // cnt2 + fill2, zeroed in prep
  int*   cnt2  = zeros;
  int*   fill2 = zeros + 2*NN;
  int*   bsum  = (int*)alloc((size_t)2*NB_SCAN*4);
  u16*   h0    = (u16*)alloc((size_t)NN*64*2);
  u16*   h1    = (u16*)alloc((size_t)NN*256*2);
  u16*   h2    = (u16*)alloc((size_t)NN*256*2);
  float* elA   = (float*)alloc((size_t)2*NN*4*4);
  float* erA   = (float*)alloc((size_t)2*NN*4*4);
  float* xbuf  = (float*)alloc((size_t)2*EE*4*4);     // 12.8 MB, reused L0/L1
  // region D (51.2 MB): layer-0 aggB -> layer-1 featD -> layer-2 outputs
  size_t featStride = (size_t)NN*256;                 // u16 elements per graph
  size_t off_D = off;
  u16* regionD = (u16*)alloc(2*featStride*2);
  u16* aggB  = regionD;
  u16* featD = regionD;
  u16*   feat16 = (u16*)(ws + off_D);                          // 2*NN*16 u16 (3.2 MB)
  float* resb   = (float*)(ws + off_D + (size_t)2*NN*16*2);    // 2*NN*16 f32
  float* el2    = resb + (size_t)2*NN*16;
  float* er2    = el2  + (size_t)2*NN;

  // 1. prep ∪ prep2 (one dispatch)
  k_prepAll<<<132,256,0,stream>>>(mix_w, wsoft, W0, W0p, W1, W1p, W2, res2, W2p,
                                  fc_w0, fc_w1, Fp, al0, ar0, fc_b0, fc_b1,
                                  V2p, bV, zeros);

  // 2. input projection (MFMA, + fused layer-0 el/er) ∪ edge count (one dispatch)
  k_inpcnt<<<NGRP + 2*NB_E,256,0,stream>>>(features0, features1, Fp, fc_b0, fc_b1,
                                           V2p, bV, h0, elA, erA,
                                           dst[0], dst[1], cnt2);

  // 3. CSR scan + scatter
  {
    dim3 gS(NB_SCAN, 2), gEb(NB_E, 2);
    k_scan1  <<<gS,1024,0,stream>>>(cnt2, row2, bsum);
    k_scan3  <<<gS,1024,0,stream>>>(row2, bsum);
    k_scatter2<<<gEb,256,0,stream>>>(src[0], dst[0], src[1], dst[1], row2, fill2, col2, dstOf);
  }

  dim3 gE(NB_E, 2);

  // 4. layer 0: alpha, interleaved dual-graph aggregate (2-wave blocks), head GEMM
  k_alpha4<<<gE,256,0,stream>>>(col2, dstOf, elA, erA, (size_t)NN*4, xbuf);
  k_agg0 <<<NN/2,128,0,stream>>>(row2, col2, xbuf, h0, aggB, featStride);
  k_head0<<<NGRP,256,0,stream>>>(aggB, featStride, W0p, b0, wsoft, h1);

  // 5. layer 1: feat = h1 @ W1 (MFMA), alpha, fused aggregation (2-wave blocks)
  k_gemm4<256><<<2*NGRP,256,0,stream>>>(h1, W1p, (size_t)256*256, al1, ar1, 256,
                                        featD, featStride, elA, erA, (size_t)NN*4);
  k_alpha4<<<gE,256,0,stream>>>(col2, dstOf, elA, erA, (size_t)NN*4, xbuf);
  k_aggNF<1><<<NN/2,128,0,stream>>>(row2, col2, xbuf, featD, featStride,
                                    h1, b1, wsoft, 1, h2);

  // 6. layer 2 (both graphs fused; alpha inline in agg2D; feat16 bf16)
  k_gemm2<<<NGRP,256,0,stream>>>(h2, W2p, al2, ar2, feat16, resb, el2, er2);
  k_agg2D<<<NN/16,256,0,stream>>>(row2, col2, el2, er2, feat16, resb, b2, wsoft, (float*)d_out);
}

// Round 4
// 426.162 us; speedup vs baseline: 1.0314x; 1.0314x over previous
//
#include <hip/hip_runtime.h>
#include <hip/hip_bf16.h>

// Problem constants (match reference)
#define NN   50000   // N0+N1
#define NN0  30000
#define EE   400000
#define NB_SCAN ((NN + 1023) / 1024)   // 49
#define NB_E  ((EE + 255) / 256)       // 1563
#define NRT   3125                     // row tiles (16 rows each)
#define NGRP  ((NRT + 3) / 4)          // 782 row groups (64 rows)
#define NGRP2 1563                     // ceil(NRT/2) row pair-groups (gemm4)
#define NT0   1875                     // type-0 row tiles (30000/16, exact)

typedef unsigned short u16;
typedef unsigned int   u32;

typedef __attribute__((ext_vector_type(8))) __bf16 bf16x8;
typedef __attribute__((ext_vector_type(4))) float  f32x4;
typedef __attribute__((ext_vector_type(2))) float  f32x2;

// ---------- bf16 storage helpers (fp32 math everywhere) ----------
__device__ __forceinline__ float bf2f(u16 u){ return __uint_as_float(((u32)u)<<16); }
__device__ __forceinline__ float lo16(u32 u){ return __uint_as_float(u<<16); }
__device__ __forceinline__ float hi16(u32 u){ return __uint_as_float(u & 0xffff0000u); }
__device__ __forceinline__ u16 f2bf(float f){
  u32 x = __float_as_uint(f);
  x += 0x7fffu + ((x>>16)&1u);      // round-to-nearest-even
  return (u16)(x>>16);
}
__device__ __forceinline__ float elu_f(float x){ return x>0.f ? x : __expf(x)-1.f; }
__device__ __forceinline__ float lrelu(float x){ return x>0.f ? x : 0.2f*x; }
__device__ __forceinline__ bf16x8 ld_frag(const u16* p){
  uint4 v = *(const uint4*)p;
  return __builtin_bit_cast(bf16x8, v);
}
__device__ __forceinline__ bf16x8 cvt8(const float* p){   // 8 f32 -> bf16x8
  float4 u = ((const float4*)p)[0];
  float4 v = ((const float4*)p)[1];
  u32 w0 = (u32)f2bf(u.x) | ((u32)f2bf(u.y)<<16);
  u32 w1 = (u32)f2bf(u.z) | ((u32)f2bf(u.w)<<16);
  u32 w2 = (u32)f2bf(v.x) | ((u32)f2bf(v.y)<<16);
  u32 w3 = (u32)f2bf(v.z) | ((u32)f2bf(v.w)<<16);
  uint4 r{w0,w1,w2,w3};
  return __builtin_bit_cast(bf16x8, r);
}
// accumulate 8 bf16 cols (uint4) weighted by x into 4 f32x2 pairs via v_pk_fma_f32
__device__ __forceinline__ void acc8pk(f32x2* p, float& den, float x, uint4 f){
  den += x;
  f32x2 xx = {x, x};
  f32x2 t0 = {lo16(f.x), hi16(f.x)};
  f32x2 t1 = {lo16(f.y), hi16(f.y)};
  f32x2 t2 = {lo16(f.z), hi16(f.z)};
  f32x2 t3 = {lo16(f.w), hi16(f.w)};
  p[0] = __builtin_elementwise_fma(t0, xx, p[0]);
  p[1] = __builtin_elementwise_fma(t1, xx, p[1]);
  p[2] = __builtin_elementwise_fma(t2, xx, p[2]);
  p[3] = __builtin_elementwise_fma(t3, xx, p[3]);
}
// accumulate 2 bf16 cols (u32) into 4 head accumulators (pk_fma) + packed dens
__device__ __forceinline__ void acc2x4(f32x2* a, f32x2& d01, f32x2& d23, float4 x, u32 w){
  f32x2 v = {lo16(w), hi16(w)};
  f32x2 x0 = {x.x, x.x}, x1 = {x.y, x.y}, x2 = {x.z, x.z}, x3 = {x.w, x.w};
  a[0] = __builtin_elementwise_fma(v, x0, a[0]);
  a[1] = __builtin_elementwise_fma(v, x1, a[1]);
  a[2] = __builtin_elementwise_fma(v, x2, a[2]);
  a[3] = __builtin_elementwise_fma(v, x3, a[3]);
  f32x2 p01 = {x.x, x.y}, p23 = {x.z, x.w};
  d01 += p01; d23 += p23;
}

// ---------- prep (blocks 0..99) ∪ prep2 (blocks 100..131) ----------
// prep: zero counters + mixw softmax + all weight packing
// prep2: V2 = fc_w @ [W0*al | W0*ar] (128x16 per type) + bV
__global__ __launch_bounds__(256) void k_prepAll(
    const float* __restrict__ mix_w, float* __restrict__ wsoft,
    const float* __restrict__ W0, u16* __restrict__ W0p,
    const float* __restrict__ W1, u16* __restrict__ W1p,
    const float* __restrict__ W2, const float* __restrict__ res2, u16* __restrict__ W2p,
    const float* __restrict__ fcw0, const float* __restrict__ fcw1, u16* __restrict__ Fp,
    const float* __restrict__ al0, const float* __restrict__ ar0,
    const float* __restrict__ fcb0, const float* __restrict__ fcb1,
    u16* __restrict__ V2p, float* __restrict__ bV,
    int* __restrict__ zeros)
{
  __shared__ float V[64];
  if (blockIdx.x >= 100){
    // ---- prep2 part: 32 blocks ----
    int b = blockIdx.x - 100;
    int tt = b>>4, cl = b&15;
    int which = cl>>3, g = (cl>>2)&1, h = cl&3;
    int t = threadIdx.x;
    const float* sel = (which ? ar0 : al0) + (size_t)(g*4+h)*64;
    if (t < 64){
      const float* Wrow = W0 + (size_t)g*16384 + (size_t)t*256 + h*64;
      float s = 0.f;
      #pragma unroll 8
      for (int d=0; d<64; d++) s = fmaf(Wrow[d], sel[d], s);
      V[t] = s;
    }
    __syncthreads();
    if (t < 128){
      const float* fw = tt ? fcw1 : fcw0;   // 128 x 64
      float s = 0.f;
      #pragma unroll 8
      for (int d=0; d<64; d++) s = fmaf(fw[(size_t)t*64 + d], V[d], s);
      int kb = t>>5, q = (t>>3)&3, j = t&7;
      V2p[(size_t)tt*2048 + ((size_t)kb*64 + q*16 + cl)*8 + j] = f2bf(s);
      if (t == 0){
        const float* fbp = tt ? fcb1 : fcb0;
        float sb = 0.f;
        #pragma unroll 8
        for (int d=0; d<64; d++) sb = fmaf(fbp[d], V[d], sb);
        bV[tt*16 + cl] = sb;
      }
    }
    return;
  }
  // ---- prep part: 100 blocks ----
  int t = blockIdx.x*256 + threadIdx.x;
  for (int z = t; z < 4*NN; z += 100*256) zeros[z] = 0;
  if (t < 6){
    float a0 = mix_w[t*2+0], a1 = mix_w[t*2+1];
    float mx = fmaxf(a0,a1);
    float e0 = __expf(a0-mx), e1 = __expf(a1-mx);
    wsoft[t*2+0] = e0/(e0+e1); wsoft[t*2+1] = e1/(e0+e1);
  }
  if (t < 4096){                    // W0: per graph 2048 frags, KB=2, NCOL=256
    int gg = t>>11, fi = t&2047;
    int lane = fi&63, kb = (fi>>6)&1, ct = fi>>7;
    int q = lane>>4, c = lane&15;
    const float* src = W0 + (size_t)gg*16384;
    u16* o = W0p + (size_t)gg*16384 + (size_t)fi*8;
    #pragma unroll
    for (int j=0;j<8;j++) o[j] = f2bf(src[(size_t)(kb*32+q*8+j)*256 + ct*16 + c]);
  } else if (t < 20480){            // W1: per graph 8192 frags, KB=8, NCOL=256
    int u = t - 4096;
    int gg = u>>13, fi = u&8191;
    int lane = fi&63, kb = (fi>>6)&7, ct = fi>>9;
    int q = lane>>4, c = lane&15;
    const float* src = W1 + (size_t)gg*65536;
    u16* o = W1p + (size_t)gg*65536 + (size_t)fi*8;
    #pragma unroll
    for (int j=0;j<8;j++) o[j] = f2bf(src[(size_t)(kb*32+q*8+j)*256 + ct*16 + c]);
  } else if (t < 22528){            // W2cat: 2048 frags, KB=8, NCOL=64
    int fi = t - 20480;
    int lane = fi&63, kb = (fi>>6)&7, ct = fi>>9;
    int q = lane>>4, c = lane&15;
    int cl = ct*16 + c;
    int i = cl>>5, which = (cl>>4)&1;
    const float* src = which ? res2 : W2;
    u16* o = W2p + (size_t)fi*8;
    #pragma unroll
    for (int j=0;j<8;j++) o[j] = f2bf(src[(size_t)i*4096 + (size_t)(kb*32+q*8+j)*16 + (cl&15)]);
  } else if (t < 24576){            // fc_w: per type 1024 frags, KB=4, NCOL=64
    int u = t - 22528;
    int tt = u>>10, fi = u&1023;
    int lane = fi&63, kb = (fi>>6)&3, ct = fi>>8;
    int q = lane>>4, c = lane&15;
    const float* src = tt ? fcw1 : fcw0;
    u16* o = Fp + (size_t)tt*8192 + (size_t)fi*8;
    #pragma unroll
    for (int j=0;j<8;j++) o[j] = f2bf(src[(size_t)(kb*32+q*8+j)*64 + ct*16 + c]);
  }
}

// ---------- fused: input projection MFMA (blocks 0..NGRP-1) ∪ edge count ------
// inproj: h0 = feats @ fc_w + fc_b;  el/er = feats @ V2 + bV
// count : cnt2[g][dst] += 1  (blocks NGRP .. NGRP+2*NB_E-1)
__global__ __launch_bounds__(256) void k_inpcnt(
    const float* __restrict__ f0, const float* __restrict__ f1,
    const u16* __restrict__ Fp, const float* __restrict__ fb0, const float* __restrict__ fb1,
    const u16* __restrict__ V2p, const float* __restrict__ bV,
    u16* __restrict__ h0, float* __restrict__ elA, float* __restrict__ erA,
    const int* __restrict__ d0, const int* __restrict__ d1, int* __restrict__ cnt2)
{
  if (blockIdx.x >= NGRP){
    int u = blockIdx.x - NGRP;
    int g = u / NB_E;
    int t = (u % NB_E)*256 + threadIdx.x;
    if (t < EE) atomicAdd(&cnt2[g*NN + (g ? d1[t] : d0[t])], 1);
    return;
  }
  int wv = threadIdx.x>>6, ln = threadIdx.x&63;
  int ti = blockIdx.x*4 + wv;
  if (ti >= NRT) return;
  int q = ln>>4, c = ln&15;
  int type = (ti < NT0) ? 0 : 1;
  const float* F = type ? f1 : f0;
  int rbase = type ? (ti*16 - NN0) : ti*16;
  const u16* Bg = Fp + (size_t)type*8192;
  const u16* Vg = V2p + (size_t)type*2048;
  const float* bb = type ? fb1 : fb0;
  f32x4 acc[4] = {};
  f32x4 accE = {};
  const float* Ap = F + (size_t)(rbase + c)*128;
  #pragma unroll
  for (int kb=0; kb<4; kb++){
    bf16x8 a = cvt8(Ap + kb*32 + q*8);
    #pragma unroll
    for (int ct=0; ct<4; ct++){
      bf16x8 b = ld_frag(Bg + ((size_t)(ct*4+kb)*64 + ln)*8);
      acc[ct] = __builtin_amdgcn_mfma_f32_16x16x32_bf16(a, b, acc[ct], 0,0,0);
    }
    bf16x8 bv_ = ld_frag(Vg + ((size_t)kb*64 + ln)*8);
    accE = __builtin_amdgcn_mfma_f32_16x16x32_bf16(a, bv_, accE, 0,0,0);
  }
  #pragma unroll
  for (int ct=0; ct<4; ct++){
    float bvs = bb[ct*16+c];
    #pragma unroll
    for (int j=0;j<4;j++){
      int row = ti*16 + q*4 + j;
      h0[(size_t)row*64 + ct*16 + c] = f2bf(acc[ct][j] + bvs);
    }
  }
  int which = c>>3, gg = (c>>2)&1, hh = c&3;
  float bVv = bV[type*16 + c];
  float* dst = (which ? erA : elA) + (size_t)gg*NN*4;
  #pragma unroll
  for (int j=0;j<4;j++){
    int row = ti*16 + q*4 + j;
    dst[row*4 + hh] = accE[j] + bVv;
  }
}

// ================= CSR build (both graphs, rebuilt every launch) ===============
__global__ __launch_bounds__(1024) void k_scan1(const int* __restrict__ cnt2,
                                                int* __restrict__ row2, int* __restrict__ bsum){
  __shared__ int wsum[16];
  int g = blockIdx.y;
  int lane = threadIdx.x & 63, wid = threadIdx.x >> 6;
  int i = blockIdx.x*1024 + threadIdx.x;
  int v = (i < NN) ? cnt2[g*NN + i] : 0;
  int x = v;
  #pragma unroll
  for (int off = 1; off < 64; off <<= 1){
    int y = __shfl_up(x, off, 64);
    if (lane >= off) x += y;
  }
  if (lane == 63) wsum[wid] = x;
  __syncthreads();
  if (wid == 0 && lane < 16){
    int s = wsum[lane];
    #pragma unroll
    for (int off = 1; off < 16; off <<= 1){
      int y = __shfl_up(s, off, 16);
      if (lane >= off) s += y;
    }
    wsum[lane] = s;
  }
  __syncthreads();
  int incl = x + (wid ? wsum[wid-1] : 0);
  if (i < NN) row2[(size_t)g*(NN+1) + i] = incl - v;
  if (threadIdx.x == 1023) bsum[g*NB_SCAN + blockIdx.x] = incl;
}

__global__ __launch_bounds__(1024) void k_scan3(int* __restrict__ row2,
                                                const int* __restrict__ bsum){
  __shared__ int base;
  int g = blockIdx.y;
  if (threadIdx.x < 64){
    int lane = threadIdx.x;
    int v = (lane < (int)blockIdx.x) ? bsum[g*NB_SCAN + lane] : 0;
    #pragma unroll
    for (int off = 32; off; off >>= 1) v += __shfl_xor(v, off, 64);
    if (lane == 0) base = v;
  }
  __syncthreads();
  int i = blockIdx.x*1024 + threadIdx.x;
  if (i < NN) row2[(size_t)g*(NN+1) + i] += base;
  if (blockIdx.x == 0 && threadIdx.x == 0) row2[(size_t)g*(NN+1) + NN] = EE;
}

__global__ void k_scatter2(const int* __restrict__ s0, const int* __restrict__ d0,
                           const int* __restrict__ s1, const int* __restrict__ d1,
                           const int* __restrict__ row2, int* __restrict__ fill2,
                           u16* __restrict__ col2, u16* __restrict__ dstOf){
  int t = blockIdx.x*256 + threadIdx.x;
  int g = blockIdx.y;
  if (t >= EE) return;
  int d = g ? d1[t] : d0[t];
  int s = g ? s1[t] : s0[t];
  int pos = atomicAdd(&fill2[g*NN + d], 1);
  size_t slot = (size_t)g*EE + row2[(size_t)g*(NN+1) + d] + pos;
  col2[slot]  = (u16)s;
  dstOf[slot] = (u16)d;
}

// ---------- alpha precompute (H=4), edge-parallel ----------
__global__ void k_alpha4(const u16* __restrict__ col2, const u16* __restrict__ dstOf,
                         const float* __restrict__ el, const float* __restrict__ er,
                         size_t elStride, float* __restrict__ xbuf){
  int t = blockIdx.x*256 + threadIdx.x;
  int g = blockIdx.y;
  if (t >= EE) return;
  size_t slot = (size_t)g*EE + t;
  int s = col2[slot], d = dstOf[slot];
  const float* elg = el + (size_t)g*elStride;
  const float* erg = er + (size_t)g*elStride;
  float4 e4 = ((const float4*)elg)[s];
  float4 r4 = ((const float4*)erg)[d];
  float4 x;
  x.x = __expf(lrelu(e4.x + r4.x));
  x.y = __expf(lrelu(e4.y + r4.y));
  x.z = __expf(lrelu(e4.z + r4.z));
  x.w = __expf(lrelu(e4.w + r4.w));
  ((float4*)xbuf)[slot] = x;
}

// ---------- layer-0 aggregation: gather h0 (64 cols), BOTH graphs ---------
// v3 (R2 best): half-wave edge split (lane covers 2 cols via u32), predicated
// unified loop (no tails), pk_fma accumulate. 4 edges per graph per iteration.
__global__ __launch_bounds__(128) void k_agg0(
    const int* __restrict__ row2, const u16* __restrict__ col2,
    const float* __restrict__ xbuf, const u16* __restrict__ h0,
    u16* __restrict__ aggB, size_t aggStride)
{
  int wv = threadIdx.x>>6, ln = threadIdx.x&63;
  int n = blockIdx.x*2 + wv;
  int half = ln>>5, l32 = ln&31;
  const int* rw0 = row2;
  const int* rw1 = row2 + (NN+1);
  const u16* cl0 = col2;
  const u16* cl1 = col2 + EE;
  const float4* xb0 = (const float4*)xbuf;
  const float4* xb1 = xb0 + EE;
  const u32* hp = (const u32*)h0;          // 32 u32 per row
  int b0_ = rw0[n], e0_ = rw0[n+1];
  int b1_ = rw1[n], e1_ = rw1[n+1];
  int n0 = e0_-b0_, n1 = e1_-b1_;
  int mx = n0>n1 ? n0 : n1;
  int iters = (mx+3)>>2;
  f32x2 aA[4] = {}; f32x2 aB[4] = {};
  f32x2 dA01 = {}, dA23 = {}, dB01 = {}, dB23 = {};
  int k0 = b0_+half, k1 = b1_+half;
  for (int it=0; it<iters; ++it){
    int i0=k0, i1=k0+2, j0=k1, j1=k1+2;
    bool v00=i0<e0_, v01=i1<e0_, v10=j0<e1_, v11=j1<e1_;
    int ci0=v00?i0:0, ci1=v01?i1:0, cj0=v10?j0:0, cj1=v11?j1:0;
    int sA0=cl0[ci0], sA1=cl0[ci1], sB0=cl1[cj0], sB1=cl1[cj1];
    float4 z = {0.f,0.f,0.f,0.f};
    float4 xA0 = v00 ? xb0[ci0] : z;
    float4 xA1 = v01 ? xb0[ci1] : z;
    float4 xB0 = v10 ? xb1[cj0] : z;
    float4 xB1 = v11 ? xb1[cj1] : z;
    u32 wA0 = hp[(size_t)sA0*32 + l32];
    u32 wA1 = hp[(size_t)sA1*32 + l32];
    u32 wB0 = hp[(size_t)sB0*32 + l32];
    u32 wB1 = hp[(size_t)sB1*32 + l32];
    acc2x4(aA, dA01, dA23, xA0, wA0);
    acc2x4(aA, dA01, dA23, xA1, wA1);
    acc2x4(aB, dB01, dB23, xB0, wB0);
    acc2x4(aB, dB01, dB23, xB1, wB1);
    k0+=4; k1+=4;
  }
  // cross-half reduction
  #pragma unroll
  for (int u=0;u<4;u++){
    aA[u].x += __shfl_xor(aA[u].x,32,64); aA[u].y += __shfl_xor(aA[u].y,32,64);
    aB[u].x += __shfl_xor(aB[u].x,32,64); aB[u].y += __shfl_xor(aB[u].y,32,64);
  }
  dA01.x += __shfl_xor(dA01.x,32,64); dA01.y += __shfl_xor(dA01.y,32,64);
  dA23.x += __shfl_xor(dA23.x,32,64); dA23.y += __shfl_xor(dA23.y,32,64);
  dB01.x += __shfl_xor(dB01.x,32,64); dB01.y += __shfl_xor(dB01.y,32,64);
  dB23.x += __shfl_xor(dB23.x,32,64); dB23.y += __shfl_xor(dB23.y,32,64);
  if (!half){
    bool hg0 = e0_ > b0_, hg1 = e1_ > b1_;
    float iA[4] = { hg0?1.f/dA01.x:0.f, hg0?1.f/dA01.y:0.f, hg0?1.f/dA23.x:0.f, hg0?1.f/dA23.y:0.f };
    float iB[4] = { hg1?1.f/dB01.x:0.f, hg1?1.f/dB01.y:0.f, hg1?1.f/dB23.x:0.f, hg1?1.f/dB23.y:0.f };
    u32* og0 = (u32*)(aggB + (size_t)n*256);
    u32* og1 = (u32*)(aggB + aggStride + (size_t)n*256);
    #pragma unroll
    for (int h=0;h<4;h++){
      u32 w0 = (u32)f2bf(aA[h].x*iA[h]) | ((u32)f2bf(aA[h].y*iA[h])<<16);
      og0[h*32 + l32] = w0;
      u32 w1 = (u32)f2bf(aB[h].x*iB[h]) | ((u32)f2bf(aB[h].y*iB[h])<<16);
      og1[h*32 + l32] = w1;
    }
  }
}

// ---------- layer-0 head GEMM: ELU(agg@W0_blockdiag + b) mixed -> h1 ----------
// v2: h-loop split across 2 block groups (2 heads each) -> 2x wave parallelism.
__global__ __launch_bounds__(256) void k_head0(
    const u16* __restrict__ aggB, size_t aggStride,
    const u16* __restrict__ W0p, const float* __restrict__ b0,
    const float* __restrict__ wsoft, u16* __restrict__ h1)
{
  int wv = threadIdx.x>>6, ln = threadIdx.x&63;
  int bg = blockIdx.x;
  int hbase = (bg / NGRP)*2;
  int ti = (bg % NGRP)*4 + wv;
  if (ti >= NRT) return;
  int q = ln>>4, c = ln&15;
  int type = (ti < NT0) ? 0 : 1;
  float wg0 = wsoft[type*6 + 0];
  float wg1 = wsoft[type*6 + 1];
  for (int h=hbase; h<hbase+2; h++){
    f32x4 acc[2][4] = {};
    #pragma unroll
    for (int g=0; g<2; g++){
      const u16* Ap = aggB + (size_t)g*aggStride + (size_t)(ti*16 + c)*256 + h*64 + q*8;
      const u16* Bg = W0p + (size_t)g*16384;
      #pragma unroll
      for (int kb=0; kb<2; kb++){
        bf16x8 a = ld_frag(Ap + kb*32);
        #pragma unroll
        for (int ct=0; ct<4; ct++){
          int ctg = h*4 + ct;
          bf16x8 b = ld_frag(Bg + ((size_t)(ctg*2 + kb)*64 + ln)*8);
          acc[g][ct] = __builtin_amdgcn_mfma_f32_16x16x32_bf16(a, b, acc[g][ct], 0,0,0);
        }
      }
    }
    #pragma unroll
    for (int ct=0; ct<4; ct++){
      int colg = h*64 + ct*16 + c;
      float bb0 = b0[colg], bb1 = b0[256 + colg];
      #pragma unroll
      for (int j=0;j<4;j++){
        int row = ti*16 + q*4 + j;
        float o = wg0*elu_f(acc[0][ct][j] + bb0) + wg1*elu_f(acc[1][ct][j] + bb1);
        h1[(size_t)row*256 + colg] = f2bf(o);
      }
    }
  }
}

// ---------- MFMA GEMM (layer 1): 2 row-tiles x 4 col-tiles per wave ------------
// v2: halved per-wave tile (was 4x4) -> 2x grid, 2x resident waves, half the
// serial latency chain per wave. Fixes 18.5% occupancy latency starvation.
template<int K>
__global__ __launch_bounds__(256) void k_gemm4(
    const u16* __restrict__ A,
    const u16* __restrict__ Bp, size_t bpStride,
    const float* __restrict__ al, const float* __restrict__ ar, int alStride,
    u16* __restrict__ feat, size_t featStride,
    float* __restrict__ el, float* __restrict__ er, size_t elStride)
{
  constexpr int KB = K/32;
  int wv = threadIdx.x>>6, ln = threadIdx.x&63;
  int bid = blockIdx.x;
  int g = bid / NGRP2, grp = bid % NGRP2;
  int split = wv, q = ln>>4, c = ln&15;
  const u16* Bpg = Bp + (size_t)g*bpStride;
  const float* alg = al + (size_t)g*alStride;
  const float* arg = ar + (size_t)g*alStride;
  u16* featg = feat + (size_t)g*featStride;
  float* elg = el + (size_t)g*elStride;
  float* erg = er + (size_t)g*elStride;

  f32x4 acc[2][4] = {};
  int  tbase = grp*2;
  bool valid[2];
  const u16* Ap[2];
  #pragma unroll
  for (int rt=0; rt<2; rt++){
    int ti = tbase + rt;
    valid[rt] = (ti < NRT);
    if (!valid[rt]) ti = NRT-1;
    Ap[rt] = A + (size_t)(ti*16 + c)*K + q*8;
  }
  const u16* Bbase = Bpg + ((size_t)(split*4)*KB*64 + ln)*8;

  #pragma unroll 2
  for (int kb=0; kb<KB; kb++){
    bf16x8 b[4], a[2];
    #pragma unroll
    for (int ct=0; ct<4; ct++) b[ct] = ld_frag(Bbase + (size_t)(ct*KB + kb)*64*8);
    #pragma unroll
    for (int rt=0; rt<2; rt++) a[rt] = ld_frag(Ap[rt] + kb*32);
    #pragma unroll
    for (int rt=0; rt<2; rt++)
      #pragma unroll
      for (int ct=0; ct<4; ct++)
        acc[rt][ct] = __builtin_amdgcn_mfma_f32_16x16x32_bf16(a[rt], b[ct], acc[rt][ct], 0,0,0);
  }

  float alv[4], arv[4];
  #pragma unroll
  for (int ct=0;ct<4;ct++){
    int cg = (split*4+ct)*16 + c;
    alv[ct] = alg[cg]; arv[ct] = arg[cg];
  }
  #pragma unroll
  for (int rt=0; rt<2; rt++){
    if (!valid[rt]) continue;
    int row0 = (tbase+rt)*16;
    #pragma unroll
    for (int j=0;j<4;j++){
      float ep=0.f, rp=0.f;
      #pragma unroll
      for (int ct=0;ct<4;ct++){ ep += acc[rt][ct][j]*alv[ct]; rp += acc[rt][ct][j]*arv[ct]; }
      #pragma unroll
      for (int off=8; off; off>>=1){ ep += __shfl_xor(ep,off,16); rp += __shfl_xor(rp,off,16); }
      int row = row0 + q*4 + j;
      if (c==0){ elg[row*4+split]=ep; erg[row*4+split]=rp; }
      #pragma unroll
      for (int ct=0;ct<4;ct++)
        featg[(size_t)row*256 + (split*4+ct)*16 + c] = f2bf(acc[rt][ct][j]);
    }
  }
}

// ---------- fused dual-graph gather aggregation (256 cols, H=4), layer 1 -------
// v3 (R2 best): half-wave split (lane covers 8 cols of one edge via uint4),
// predicated unified loop (no tails), pk_fma accumulate.
template<int RES>
__global__ __launch_bounds__(128) void k_aggNF(
    const int* __restrict__ row2, const u16* __restrict__ col2,
    const float* __restrict__ xbuf,
    const u16* __restrict__ feat, size_t featStride,
    const u16* __restrict__ hres, const float* __restrict__ bias,
    const float* __restrict__ wsoft, int l,
    u16* __restrict__ hout)
{
  int wv = threadIdx.x>>6, ln = threadIdx.x&63;
  int n = blockIdx.x*2 + wv;
  int half = ln>>5, l32 = ln&31;
  int hh = l32>>3;                       // head of this lane's 8 cols
  int type = (n<NN0)?0:1;
  const int* rw0 = row2;
  const int* rw1 = row2 + (NN+1);
  const u16* cl0 = col2;
  const u16* cl1 = col2 + EE;
  const float* x0p = xbuf;
  const float* x1p = xbuf + (size_t)EE*4;
  const uint4* fp0 = (const uint4*)feat;                  // row = 32 uint4
  const uint4* fp1 = (const uint4*)(feat + featStride);
  int b0_ = rw0[n], e0_ = rw0[n+1];
  int b1_ = rw1[n], e1_ = rw1[n+1];
  int n0 = e0_-b0_, n1 = e1_-b1_;
  int mx = n0>n1 ? n0 : n1;
  int iters = (mx+3)>>2;
  f32x2 pA[4] = {}; f32x2 pB[4] = {};
  float denA = 0.f, denB = 0.f;
  int k0 = b0_+half, k1 = b1_+half;
  for (int it=0; it<iters; ++it){
    int i0=k0, i1=k0+2, j0=k1, j1=k1+2;
    bool v00=i0<e0_, v01=i1<e0_, v10=j0<e1_, v11=j1<e1_;
    int ci0=v00?i0:0, ci1=v01?i1:0, cj0=v10?j0:0, cj1=v11?j1:0;
    int sA0=cl0[ci0], sA1=cl0[ci1], sB0=cl1[cj0], sB1=cl1[cj1];
    float xA0 = v00 ? x0p[(size_t)ci0*4+hh] : 0.f;
    float xA1 = v01 ? x0p[(size_t)ci1*4+hh] : 0.f;
    float xB0 = v10 ? x1p[(size_t)cj0*4+hh] : 0.f;
    float xB1 = v11 ? x1p[(size_t)cj1*4+hh] : 0.f;
    uint4 fA0 = fp0[(size_t)sA0*32+l32];
    uint4 fA1 = fp0[(size_t)sA1*32+l32];
    uint4 fB0 = fp1[(size_t)sB0*32+l32];
    uint4 fB1 = fp1[(size_t)sB1*32+l32];
    acc8pk(pA, denA, xA0, fA0);
    acc8pk(pA, denA, xA1, fA1);
    acc8pk(pB, denB, xB0, fB0);
    acc8pk(pB, denB, xB1, fB1);
    k0+=4; k1+=4;
  }
  // cross-half reduction (lane i and i^32 hold same cols, disjoint edges)
  #pragma unroll
  for (int u=0;u<4;u++){
    pA[u].x += __shfl_xor(pA[u].x,32,64); pA[u].y += __shfl_xor(pA[u].y,32,64);
    pB[u].x += __shfl_xor(pB[u].x,32,64); pB[u].y += __shfl_xor(pB[u].y,32,64);
  }
  denA += __shfl_xor(denA,32,64);
  denB += __shfl_xor(denB,32,64);
  if (!half){
    float accA[8], accB[8];
    #pragma unroll
    for (int u=0;u<4;u++){
      accA[2*u]=pA[u].x; accA[2*u+1]=pA[u].y;
      accB[2*u]=pB[u].x; accB[2*u+1]=pB[u].y;
    }
    float inv0 = (e0_>b0_) ? 1.0f/denA : 0.f;
    float inv1 = (e1_>b1_) ? 1.0f/denB : 0.f;
    const float4* bp0 = (const float4*)bias;
    const float4* bp1 = (const float4*)(bias + 256);
    float4 bva = bp0[l32*2], bvb = bp0[l32*2+1];
    float4 bwa = bp1[l32*2], bwb = bp1[l32*2+1];
    float bb0[8] = {bva.x,bva.y,bva.z,bva.w,bvb.x,bvb.y,bvb.z,bvb.w};
    float bb1[8] = {bwa.x,bwa.y,bwa.z,bwa.w,bwb.x,bwb.y,bwb.z,bwb.w};
    float w0 = wsoft[type*6 + l*2 + 0];
    float w1 = wsoft[type*6 + l*2 + 1];
    float r[8] = {0.f,0.f,0.f,0.f,0.f,0.f,0.f,0.f};
    if (RES){
      uint4 rr = ((const uint4*)hres)[(size_t)n*32 + l32];
      r[0]=lo16(rr.x); r[1]=hi16(rr.x); r[2]=lo16(rr.y); r[3]=hi16(rr.y);
      r[4]=lo16(rr.z); r[5]=hi16(rr.z); r[6]=lo16(rr.w); r[7]=hi16(rr.w);
    }
    u16 ov[8];
    #pragma unroll
    for (int j=0;j<8;j++){
      float c = accA[j]*inv0 + bb0[j] + r[j];
      float e = accB[j]*inv1 + bb1[j] + r[j];
      ov[j] = f2bf(w0*elu_f(c) + w1*elu_f(e));
    }
    uint4 o;
    o.x = (u32)ov[0] | ((u32)ov[1]<<16);
    o.y = (u32)ov[2] | ((u32)ov[3]<<16);
    o.z = (u32)ov[4] | ((u32)ov[5]<<16);
    o.w = (u32)ov[6] | ((u32)ov[7]<<16);
    ((uint4*)hout)[(size_t)n*32 + l32] = o;
  }
}

// ---------- layer-2 MFMA: A(N,256) @ [W2_0|res2_0|W2_1|res2_1](256,64) ----------
__global__ __launch_bounds__(256) void k_gemm2(
    const u16* __restrict__ A, const u16* __restrict__ Bp,
    const float* __restrict__ al2, const float* __restrict__ ar2,
    u16* __restrict__ feat16, float* __restrict__ resb,
    float* __restrict__ el2, float* __restrict__ er2)
{
  int wv = threadIdx.x>>6, ln = threadIdx.x&63;
  int wt = blockIdx.x*4 + wv;
  if (wt >= NRT) return;
  int row0 = wt*16;
  int q = ln>>4, c = ln&15;
  f32x4 acc[4] = {};
  const u16* Ap = A + (size_t)(row0 + c)*256 + q*8;
  #pragma unroll
  for (int kb=0; kb<8; kb++){
    bf16x8 a = ld_frag(Ap + kb*32);
    #pragma unroll
    for (int t=0;t<4;t++){
      bf16x8 b = ld_frag(Bp + ((size_t)(t*8 + kb)*64 + ln)*8);
      acc[t] = __builtin_amdgcn_mfma_f32_16x16x32_bf16(a, b, acc[t], 0,0,0);
    }
  }
  #pragma unroll
  for (int i=0;i<2;i++){
    float alv = al2[i*16+c], arv = ar2[i*16+c];
    #pragma unroll
    for (int j=0;j<4;j++){
      float ep = acc[2*i][j]*alv, rp = acc[2*i][j]*arv;
      #pragma unroll
      for (int off=8; off; off>>=1){ ep += __shfl_xor(ep,off,16); rp += __shfl_xor(rp,off,16); }
      if (c==0){
        int row = row0 + q*4 + j;
        el2[(size_t)i*NN + row] = ep; er2[(size_t)i*NN + row] = rp;
      }
    }
    #pragma unroll
    for (int j=0;j<4;j++){
      int row = row0 + q*4 + j;
      feat16[(size_t)i*NN*16 + (size_t)row*16 + c] = f2bf(acc[2*i][j]);
      resb  [(size_t)i*NN*16 + (size_t)row*16 + c] = acc[2*i+1][j];
    }
  }
}

// ---------- layer-2 dual-graph aggregation + inline alpha + final mix ----------
__global__ __launch_bounds__(256) void k_agg2D(
    const int* __restrict__ row2, const u16* __restrict__ col2,
    const float* __restrict__ el2, const float* __restrict__ er2,
    const u16* __restrict__ feat16, const float* __restrict__ resb,
    const float* __restrict__ b2, const float* __restrict__ wsoft,
    float* __restrict__ out)
{
  int t = threadIdx.x;
  int nl = t>>4, j = t&15;
  int n = blockIdx.x*16 + nl;
  int type = (n<NN0)?0:1;
  float o = 0.f;
  #pragma unroll
  for (int i=0;i<2;i++){
    const int* rw = row2 + (size_t)i*(NN+1);
    const u16* cl = col2 + (size_t)i*EE;
    const float* elg = el2 + (size_t)i*NN;
    float ern = er2[(size_t)i*NN + n];
    const u16* f = feat16 + (size_t)i*NN*16;
    int beg = rw[n], end = rw[n+1];
    float den = 0.f, acc = 0.f;
    int k = beg;
    for (; k+4<=end; k+=4){
      int s0=cl[k], s1=cl[k+1], s2=cl[k+2], s3=cl[k+3];
      float x0 = __expf(lrelu(elg[s0] + ern));
      float x1 = __expf(lrelu(elg[s1] + ern));
      float x2 = __expf(lrelu(elg[s2] + ern));
      float x3 = __expf(lrelu(elg[s3] + ern));
      float v0 = bf2f(f[(size_t)s0*16 + j]);
      float v1 = bf2f(f[(size_t)s1*16 + j]);
      float v2 = bf2f(f[(size_t)s2*16 + j]);
      float v3 = bf2f(f[(size_t)s3*16 + j]);
      den += (x0+x1) + (x2+x3);
      acc += x0*v0 + x1*v1 + x2*v2 + x3*v3;
    }
    for (; k<end; k++){
      int s = cl[k];
      float x = __expf(lrelu(elg[s] + ern));
      den += x;
      acc = fmaf(x, bf2f(f[(size_t)s*16 + j]), acc);
    }
    float inv = (end>beg) ? 1.0f/den : 0.f;
    float oi = acc*inv + b2[i*16+j] + resb[(size_t)i*NN*16 + (size_t)n*16 + j];
    o += oi * wsoft[type*6 + 4 + i];
  }
  out[(size_t)n*16 + j] = o;
}

extern "C" void kernel_launch(void* const* d_in, const int* in_sizes, int n_in,
                              void* d_out, int out_size, void* d_ws, size_t ws_size,
                              hipStream_t stream)
{
  const float* features0 = (const float*)d_in[0];
  const float* features1 = (const float*)d_in[1];
  const float* fc_w0 = (const float*)d_in[2];
  const float* fc_b0 = (const float*)d_in[3];
  const float* fc_w1 = (const float*)d_in[4];
  const float* fc_b1 = (const float*)d_in[5];
  const float* mix_w = (const float*)d_in[6];
  const float* W0  = (const float*)d_in[7];
  const float* al0 = (const float*)d_in[8];
  const float* ar0 = (const float*)d_in[9];
  const float* b0  = (const float*)d_in[10];
  const float* W1  = (const float*)d_in[11];
  const float* al1 = (const float*)d_in[12];
  const float* ar1 = (const float*)d_in[13];
  const float* b1  = (const float*)d_in[14];
  const float* W2  = (const float*)d_in[15];
  const float* al2 = (const float*)d_in[16];
  const float* ar2 = (const float*)d_in[17];
  const float* b2  = (const float*)d_in[18];
  const float* res2= (const float*)d_in[19];
  const int* src[2] = {(const int*)d_in[20], (const int*)d_in[22]};
  const int* dst[2] = {(const int*)d_in[21], (const int*)d_in[23]};
  (void)in_sizes; (void)n_in; (void)out_size; (void)ws_size;

  char* ws = (char*)d_ws;
  size_t off = 0;
  auto alloc = [&](size_t bytes)->char*{
    char* p = ws + off; off += (bytes + 255) & ~(size_t)255; return p;
  };
  float* wsoft = (float*)alloc(64*4);
  u16*   W0p   = (u16*)  alloc((size_t)2*64*256*2);
  u16*   W1p   = (u16*)  alloc((size_t)2*256*256*2);
  u16*   W2p   = (u16*)  alloc((size_t)256*64*2);
  u16*   Fp    = (u16*)  alloc((size_t)2*128*64*2);
  u16*   V2p   = (u16*)  alloc((size_t)2*128*16*2);
  float* bV    = (float*)alloc((size_t)32*4);
  int*   row2  = (int*)  alloc((size_t)2*(NN+1)*4);
  u16*   col2  = (u16*)  alloc((size_t)2*EE*2);
  u16*   dstOf = (u16*)  alloc((size_t)2*EE*2);
  int*   zeros = (int*)  alloc((size_t)4*NN*4);       // cnt2 + fill2, zeroed in prep
  int*   cnt2  = zeros;
  int*   fill2 = zeros + 2*NN;
  int*   bsum  = (int*)alloc((size_t)2*NB_SCAN*4);
  u16*   h0    = (u16*)alloc((size_t)NN*64*2);
  u16*   h1    = (u16*)alloc((size_t)NN*256*2);
  u16*   h2    = (u16*)alloc((size_t)NN*256*2);
  float* elA   = (float*)alloc((size_t)2*NN*4*4);
  float* erA   = (float*)alloc((size_t)2*NN*4*4);
  float* xbuf  = (float*)alloc((size_t)2*EE*4*4);     // 12.8 MB, reused L0/L1
  // region D (51.2 MB): layer-0 aggB -> layer-1 featD -> layer-2 outputs
  size_t featStride = (size_t)NN*256;                 // u16 elements per graph
  size_t off_D = off;
  u16* regionD = (u16*)alloc(2*featStride*2);
  u16* aggB  = regionD;
  u16* featD = regionD;
  u16*   feat16 = (u16*)(ws + off_D);                          // 2*NN*16 u16 (3.2 MB)
  float* resb   = (float*)(ws + off_D + (size_t)2*NN*16*2);    // 2*NN*16 f32
  float* el2    = resb + (size_t)2*NN*16;
  float* er2    = el2  + (size_t)2*NN;

  // 1. prep ∪ prep2 (one dispatch)
  k_prepAll<<<132,256,0,stream>>>(mix_w, wsoft, W0, W0p, W1, W1p, W2, res2, W2p,
                                  fc_w0, fc_w1, Fp, al0, ar0, fc_b0, fc_b1,
                                  V2p, bV, zeros);

  // 2. input projection (MFMA, + fused layer-0 el/er) ∪ edge count (one dispatch)
  k_inpcnt<<<NGRP + 2*NB_E,256,0,stream>>>(features0, features1, Fp, fc_b0, fc_b1,
                                           V2p, bV, h0, elA, erA,
                                           dst[0], dst[1], cnt2);

  // 3. CSR scan + scatter
  {
    dim3 gS(NB_SCAN, 2), gEb(NB_E, 2);
    k_scan1  <<<gS,1024,0,stream>>>(cnt2, row2, bsum);
    k_scan3  <<<gS,1024,0,stream>>>(row2, bsum);
    k_scatter2<<<gEb,256,0,stream>>>(src[0], dst[0], src[1], dst[1], row2, fill2, col2, dstOf);
  }

  dim3 gE(NB_E, 2);

  // 4. layer 0: alpha, interleaved dual-graph aggregate (2-wave blocks), head GEMM
  k_alpha4<<<gE,256,0,stream>>>(col2, dstOf, elA, erA, (size_t)NN*4, xbuf);
  k_agg0 <<<NN/2,128,0,stream>>>(row2, col2, xbuf, h0, aggB, featStride);
  k_head0<<<2*NGRP,256,0,stream>>>(aggB, featStride, W0p, b0, wsoft, h1);

  // 5. layer 1: feat = h1 @ W1 (MFMA), alpha, fused aggregation (2-wave blocks)
  k_gemm4<256><<<2*NGRP2,256,0,stream>>>(h1, W1p, (size_t)256*256, al1, ar1, 256,
                                         featD, featStride, elA, erA, (size_t)NN*4);
  k_alpha4<<<gE,256,0,stream>>>(col2, dstOf, elA, erA, (size_t)NN*4, xbuf);
  k_aggNF<1><<<NN/2,128,0,stream>>>(row2, col2, xbuf, featD, featStride,
                                    h1, b1, wsoft, 1, h2);

  // 6. layer 2 (both graphs fused; alpha inline in agg2D; feat16 bf16)
  k_gemm2<<<NGRP,256,0,stream>>>(h2, W2p, al2, ar2, feat16, resb, el2, er2);
  k_agg2D<<<NN/16,256,0,stream>>>(row2, col2, el2, er2, feat16, resb, b2, wsoft, (float*)d_out);
}

// Round 5
// 418.182 us; speedup vs baseline: 1.0511x; 1.0191x over previous
//
#include <hip/hip_runtime.h>
#include <hip/hip_bf16.h>

// Problem constants (match reference)
#define NN   50000   // N0+N1
#define NN0  30000
#define EE   400000
#define NB_SCAN ((NN + 1023) / 1024)   // 49
#define NB_E  ((EE + 255) / 256)       // 1563
#define NRT   3125                     // row tiles (16 rows each)
#define NGRP  ((NRT + 3) / 4)          // 782 row groups (64 rows)
#define NGRP2 1563                     // ceil(NRT/2) row pair-groups (gemm4)
#define NT0   1875                     // type-0 row tiles (30000/16, exact)

typedef unsigned short u16;
typedef unsigned int   u32;

typedef __attribute__((ext_vector_type(8))) __bf16 bf16x8;
typedef __attribute__((ext_vector_type(4))) float  f32x4;
typedef __attribute__((ext_vector_type(2))) float  f32x2;

// ---------- bf16 storage helpers (fp32 math everywhere) ----------
__device__ __forceinline__ float bf2f(u16 u){ return __uint_as_float(((u32)u)<<16); }
__device__ __forceinline__ float lo16(u32 u){ return __uint_as_float(u<<16); }
__device__ __forceinline__ float hi16(u32 u){ return __uint_as_float(u & 0xffff0000u); }
__device__ __forceinline__ u16 f2bf(float f){
  u32 x = __float_as_uint(f);
  x += 0x7fffu + ((x>>16)&1u);      // round-to-nearest-even
  return (u16)(x>>16);
}
__device__ __forceinline__ float elu_f(float x){ return x>0.f ? x : __expf(x)-1.f; }
__device__ __forceinline__ float lrelu(float x){ return x>0.f ? x : 0.2f*x; }
__device__ __forceinline__ bf16x8 ld_frag(const u16* p){
  uint4 v = *(const uint4*)p;
  return __builtin_bit_cast(bf16x8, v);
}
__device__ __forceinline__ bf16x8 cvt8(const float* p){   // 8 f32 -> bf16x8
  float4 u = ((const float4*)p)[0];
  float4 v = ((const float4*)p)[1];
  u32 w0 = (u32)f2bf(u.x) | ((u32)f2bf(u.y)<<16);
  u32 w1 = (u32)f2bf(u.z) | ((u32)f2bf(u.w)<<16);
  u32 w2 = (u32)f2bf(v.x) | ((u32)f2bf(v.y)<<16);
  u32 w3 = (u32)f2bf(v.z) | ((u32)f2bf(v.w)<<16);
  uint4 r{w0,w1,w2,w3};
  return __builtin_bit_cast(bf16x8, r);
}
// 32-bit-offset load helpers (keep base uniform -> SGPR base + VGPR voffset)
__device__ __forceinline__ u32   ld_u16o (const char* b, u32 o){ return *(const u16*)(b + o); }
__device__ __forceinline__ u32   ld_u32o (const char* b, u32 o){ return *(const u32*)(b + o); }
__device__ __forceinline__ float ld_f32o (const char* b, u32 o){ return *(const float*)(b + o); }
__device__ __forceinline__ float4 ld_f4o (const char* b, u32 o){ return *(const float4*)(b + o); }
__device__ __forceinline__ uint4  ld_u4o (const char* b, u32 o){ return *(const uint4*)(b + o); }
// accumulate 8 bf16 cols (uint4) weighted by x into 4 f32x2 pairs via v_pk_fma_f32
__device__ __forceinline__ void acc8pk(f32x2* p, float& den, float x, uint4 f){
  den += x;
  f32x2 xx = {x, x};
  f32x2 t0 = {lo16(f.x), hi16(f.x)};
  f32x2 t1 = {lo16(f.y), hi16(f.y)};
  f32x2 t2 = {lo16(f.z), hi16(f.z)};
  f32x2 t3 = {lo16(f.w), hi16(f.w)};
  p[0] = __builtin_elementwise_fma(t0, xx, p[0]);
  p[1] = __builtin_elementwise_fma(t1, xx, p[1]);
  p[2] = __builtin_elementwise_fma(t2, xx, p[2]);
  p[3] = __builtin_elementwise_fma(t3, xx, p[3]);
}
// accumulate 2 bf16 cols (u32) into 4 head accumulators (pk_fma) + packed dens
__device__ __forceinline__ void acc2x4(f32x2* a, f32x2& d01, f32x2& d23, float4 x, u32 w){
  f32x2 v = {lo16(w), hi16(w)};
  f32x2 x0 = {x.x, x.x}, x1 = {x.y, x.y}, x2 = {x.z, x.z}, x3 = {x.w, x.w};
  a[0] = __builtin_elementwise_fma(v, x0, a[0]);
  a[1] = __builtin_elementwise_fma(v, x1, a[1]);
  a[2] = __builtin_elementwise_fma(v, x2, a[2]);
  a[3] = __builtin_elementwise_fma(v, x3, a[3]);
  f32x2 p01 = {x.x, x.y}, p23 = {x.z, x.w};
  d01 += p01; d23 += p23;
}

// ---------- prep (blocks 0..99) ∪ prep2 (blocks 100..131) ----------
__global__ __launch_bounds__(256) void k_prepAll(
    const float* __restrict__ mix_w, float* __restrict__ wsoft,
    const float* __restrict__ W0, u16* __restrict__ W0p,
    const float* __restrict__ W1, u16* __restrict__ W1p,
    const float* __restrict__ W2, const float* __restrict__ res2, u16* __restrict__ W2p,
    const float* __restrict__ fcw0, const float* __restrict__ fcw1, u16* __restrict__ Fp,
    const float* __restrict__ al0, const float* __restrict__ ar0,
    const float* __restrict__ fcb0, const float* __restrict__ fcb1,
    u16* __restrict__ V2p, float* __restrict__ bV,
    int* __restrict__ zeros)
{
  __shared__ float V[64];
  if (blockIdx.x >= 100){
    // ---- prep2 part: 32 blocks ----
    int b = blockIdx.x - 100;
    int tt = b>>4, cl = b&15;
    int which = cl>>3, g = (cl>>2)&1, h = cl&3;
    int t = threadIdx.x;
    const float* sel = (which ? ar0 : al0) + (size_t)(g*4+h)*64;
    if (t < 64){
      const float* Wrow = W0 + (size_t)g*16384 + (size_t)t*256 + h*64;
      float s = 0.f;
      #pragma unroll 8
      for (int d=0; d<64; d++) s = fmaf(Wrow[d], sel[d], s);
      V[t] = s;
    }
    __syncthreads();
    if (t < 128){
      const float* fw = tt ? fcw1 : fcw0;   // 128 x 64
      float s = 0.f;
      #pragma unroll 8
      for (int d=0; d<64; d++) s = fmaf(fw[(size_t)t*64 + d], V[d], s);
      int kb = t>>5, q = (t>>3)&3, j = t&7;
      V2p[(size_t)tt*2048 + ((size_t)kb*64 + q*16 + cl)*8 + j] = f2bf(s);
      if (t == 0){
        const float* fbp = tt ? fcb1 : fcb0;
        float sb = 0.f;
        #pragma unroll 8
        for (int d=0; d<64; d++) sb = fmaf(fbp[d], V[d], sb);
        bV[tt*16 + cl] = sb;
      }
    }
    return;
  }
  // ---- prep part: 100 blocks ----
  int t = blockIdx.x*256 + threadIdx.x;
  for (int z = t; z < 4*NN; z += 100*256) zeros[z] = 0;
  if (t < 6){
    float a0 = mix_w[t*2+0], a1 = mix_w[t*2+1];
    float mx = fmaxf(a0,a1);
    float e0 = __expf(a0-mx), e1 = __expf(a1-mx);
    wsoft[t*2+0] = e0/(e0+e1); wsoft[t*2+1] = e1/(e0+e1);
  }
  if (t < 4096){                    // W0: per graph 2048 frags, KB=2, NCOL=256
    int gg = t>>11, fi = t&2047;
    int lane = fi&63, kb = (fi>>6)&1, ct = fi>>7;
    int q = lane>>4, c = lane&15;
    const float* src = W0 + (size_t)gg*16384;
    u16* o = W0p + (size_t)gg*16384 + (size_t)fi*8;
    #pragma unroll
    for (int j=0;j<8;j++) o[j] = f2bf(src[(size_t)(kb*32+q*8+j)*256 + ct*16 + c]);
  } else if (t < 20480){            // W1: per graph 8192 frags, KB=8, NCOL=256
    int u = t - 4096;
    int gg = u>>13, fi = u&8191;
    int lane = fi&63, kb = (fi>>6)&7, ct = fi>>9;
    int q = lane>>4, c = lane&15;
    const float* src = W1 + (size_t)gg*65536;
    u16* o = W1p + (size_t)gg*65536 + (size_t)fi*8;
    #pragma unroll
    for (int j=0;j<8;j++) o[j] = f2bf(src[(size_t)(kb*32+q*8+j)*256 + ct*16 + c]);
  } else if (t < 22528){            // W2cat: 2048 frags, KB=8, NCOL=64
    int fi = t - 20480;
    int lane = fi&63, kb = (fi>>6)&7, ct = fi>>9;
    int q = lane>>4, c = lane&15;
    int cl = ct*16 + c;
    int i = cl>>5, which = (cl>>4)&1;
    const float* src = which ? res2 : W2;
    u16* o = W2p + (size_t)fi*8;
    #pragma unroll
    for (int j=0;j<8;j++) o[j] = f2bf(src[(size_t)i*4096 + (size_t)(kb*32+q*8+j)*16 + (cl&15)]);
  } else if (t < 24576){            // fc_w: per type 1024 frags, KB=4, NCOL=64
    int u = t - 22528;
    int tt = u>>10, fi = u&1023;
    int lane = fi&63, kb = (fi>>6)&3, ct = fi>>8;
    int q = lane>>4, c = lane&15;
    const float* src = tt ? fcw1 : fcw0;
    u16* o = Fp + (size_t)tt*8192 + (size_t)fi*8;
    #pragma unroll
    for (int j=0;j<8;j++) o[j] = f2bf(src[(size_t)(kb*32+q*8+j)*64 + ct*16 + c]);
  }
}

// ---------- fused: input projection MFMA (blocks 0..NGRP-1) ∪ edge count ------
__global__ __launch_bounds__(256) void k_inpcnt(
    const float* __restrict__ f0, const float* __restrict__ f1,
    const u16* __restrict__ Fp, const float* __restrict__ fb0, const float* __restrict__ fb1,
    const u16* __restrict__ V2p, const float* __restrict__ bV,
    u16* __restrict__ h0, float* __restrict__ elA, float* __restrict__ erA,
    const int* __restrict__ d0, const int* __restrict__ d1, int* __restrict__ cnt2)
{
  if (blockIdx.x >= NGRP){
    int u = blockIdx.x - NGRP;
    int g = u / NB_E;
    int t = (u % NB_E)*256 + threadIdx.x;
    if (t < EE) atomicAdd(&cnt2[g*NN + (g ? d1[t] : d0[t])], 1);
    return;
  }
  int wv = threadIdx.x>>6, ln = threadIdx.x&63;
  int ti = blockIdx.x*4 + wv;
  if (ti >= NRT) return;
  int q = ln>>4, c = ln&15;
  int type = (ti < NT0) ? 0 : 1;
  const float* F = type ? f1 : f0;
  int rbase = type ? (ti*16 - NN0) : ti*16;
  const u16* Bg = Fp + (size_t)type*8192;
  const u16* Vg = V2p + (size_t)type*2048;
  const float* bb = type ? fb1 : fb0;
  f32x4 acc[4] = {};
  f32x4 accE = {};
  const float* Ap = F + (size_t)(rbase + c)*128;
  #pragma unroll
  for (int kb=0; kb<4; kb++){
    bf16x8 a = cvt8(Ap + kb*32 + q*8);
    #pragma unroll
    for (int ct=0; ct<4; ct++){
      bf16x8 b = ld_frag(Bg + ((size_t)(ct*4+kb)*64 + ln)*8);
      acc[ct] = __builtin_amdgcn_mfma_f32_16x16x32_bf16(a, b, acc[ct], 0,0,0);
    }
    bf16x8 bv_ = ld_frag(Vg + ((size_t)kb*64 + ln)*8);
    accE = __builtin_amdgcn_mfma_f32_16x16x32_bf16(a, bv_, accE, 0,0,0);
  }
  #pragma unroll
  for (int ct=0; ct<4; ct++){
    float bvs = bb[ct*16+c];
    #pragma unroll
    for (int j=0;j<4;j++){
      int row = ti*16 + q*4 + j;
      h0[(size_t)row*64 + ct*16 + c] = f2bf(acc[ct][j] + bvs);
    }
  }
  int which = c>>3, gg = (c>>2)&1, hh = c&3;
  float bVv = bV[type*16 + c];
  float* dst = (which ? erA : elA) + (size_t)gg*NN*4;
  #pragma unroll
  for (int j=0;j<4;j++){
    int row = ti*16 + q*4 + j;
    dst[row*4 + hh] = accE[j] + bVv;
  }
}

// ================= CSR build (both graphs, rebuilt every launch) ===============
__global__ __launch_bounds__(1024) void k_scan1(const int* __restrict__ cnt2,
                                                int* __restrict__ row2, int* __restrict__ bsum){
  __shared__ int wsum[16];
  int g = blockIdx.y;
  int lane = threadIdx.x & 63, wid = threadIdx.x >> 6;
  int i = blockIdx.x*1024 + threadIdx.x;
  int v = (i < NN) ? cnt2[g*NN + i] : 0;
  int x = v;
  #pragma unroll
  for (int off = 1; off < 64; off <<= 1){
    int y = __shfl_up(x, off, 64);
    if (lane >= off) x += y;
  }
  if (lane == 63) wsum[wid] = x;
  __syncthreads();
  if (wid == 0 && lane < 16){
    int s = wsum[lane];
    #pragma unroll
    for (int off = 1; off < 16; off <<= 1){
      int y = __shfl_up(s, off, 16);
      if (lane >= off) s += y;
    }
    wsum[lane] = s;
  }
  __syncthreads();
  int incl = x + (wid ? wsum[wid-1] : 0);
  if (i < NN) row2[(size_t)g*(NN+1) + i] = incl - v;
  if (threadIdx.x == 1023) bsum[g*NB_SCAN + blockIdx.x] = incl;
}

__global__ __launch_bounds__(1024) void k_scan3(int* __restrict__ row2,
                                                const int* __restrict__ bsum){
  __shared__ int base;
  int g = blockIdx.y;
  if (threadIdx.x < 64){
    int lane = threadIdx.x;
    int v = (lane < (int)blockIdx.x) ? bsum[g*NB_SCAN + lane] : 0;
    #pragma unroll
    for (int off = 32; off; off >>= 1) v += __shfl_xor(v, off, 64);
    if (lane == 0) base = v;
  }
  __syncthreads();
  int i = blockIdx.x*1024 + threadIdx.x;
  if (i < NN) row2[(size_t)g*(NN+1) + i] += base;
  if (blockIdx.x == 0 && threadIdx.x == 0) row2[(size_t)g*(NN+1) + NN] = EE;
}

__global__ void k_scatter2(const int* __restrict__ s0, const int* __restrict__ d0,
                           const int* __restrict__ s1, const int* __restrict__ d1,
                           const int* __restrict__ row2, int* __restrict__ fill2,
                           u16* __restrict__ col2, u16* __restrict__ dstOf){
  int t = blockIdx.x*256 + threadIdx.x;
  int g = blockIdx.y;
  if (t >= EE) return;
  int d = g ? d1[t] : d0[t];
  int s = g ? s1[t] : s0[t];
  int pos = atomicAdd(&fill2[g*NN + d], 1);
  size_t slot = (size_t)g*EE + row2[(size_t)g*(NN+1) + d] + pos;
  col2[slot]  = (u16)s;
  dstOf[slot] = (u16)d;
}

// ---------- alpha precompute (H=4), edge-parallel (32-bit offset addressing) --
__global__ void k_alpha4(const u16* __restrict__ col2, const u16* __restrict__ dstOf,
                         const float* __restrict__ el, const float* __restrict__ er,
                         size_t elStride, float* __restrict__ xbuf){
  int t = blockIdx.x*256 + threadIdx.x;
  int g = blockIdx.y;
  if (t >= EE) return;
  size_t slot = (size_t)g*EE + t;
  u32 s = col2[slot], d = dstOf[slot];
  const char* elg = (const char*)(el + (size_t)g*elStride);
  const char* erg = (const char*)(er + (size_t)g*elStride);
  float4 e4 = ld_f4o(elg, s<<4);
  float4 r4 = ld_f4o(erg, d<<4);
  float4 x;
  x.x = __expf(lrelu(e4.x + r4.x));
  x.y = __expf(lrelu(e4.y + r4.y));
  x.z = __expf(lrelu(e4.z + r4.z));
  x.w = __expf(lrelu(e4.w + r4.w));
  ((float4*)xbuf)[slot] = x;
}

// ---------- layer-0 aggregation: gather h0 (64 cols), BOTH graphs ---------
// v5: R2-v3 structure + 32-bit byte-offset addressing on all hot loads.
__global__ __launch_bounds__(128) void k_agg0(
    const int* __restrict__ row2, const u16* __restrict__ col2,
    const float* __restrict__ xbuf, const u16* __restrict__ h0,
    u16* __restrict__ aggB, size_t aggStride)
{
  int wv = threadIdx.x>>6, ln = threadIdx.x&63;
  int n = blockIdx.x*2 + wv;
  int half = ln>>5, l32 = ln&31;
  u32 coloff = (u32)l32<<2;                 // byte offset within 128B h0 row
  const char* cl0 = (const char*)col2;
  const char* cl1 = (const char*)(col2 + EE);
  const char* xb0 = (const char*)xbuf;                       // float4/edge
  const char* xb1 = xb0 + (size_t)EE*16;
  const char* hp  = (const char*)h0;                         // 128B rows
  int b0_ = row2[n], e0_ = row2[n+1];
  int b1_ = row2[(NN+1)+n], e1_ = row2[(NN+1)+n+1];
  int n0 = e0_-b0_, n1 = e1_-b1_;
  int mx = n0>n1 ? n0 : n1;
  int iters = (mx+3)>>2;
  f32x2 aA[4] = {}; f32x2 aB[4] = {};
  f32x2 dA01 = {}, dA23 = {}, dB01 = {}, dB23 = {};
  int k0 = b0_+half, k1 = b1_+half;
  for (int it=0; it<iters; ++it){
    int i0=k0, i1=k0+2, j0=k1, j1=k1+2;
    bool v00=i0<e0_, v01=i1<e0_, v10=j0<e1_, v11=j1<e1_;
    u32 ci0=v00?(u32)i0:0u, ci1=v01?(u32)i1:0u, cj0=v10?(u32)j0:0u, cj1=v11?(u32)j1:0u;
    u32 sA0=ld_u16o(cl0,ci0<<1), sA1=ld_u16o(cl0,ci1<<1);
    u32 sB0=ld_u16o(cl1,cj0<<1), sB1=ld_u16o(cl1,cj1<<1);
    float4 z = {0.f,0.f,0.f,0.f};
    float4 xA0 = v00 ? ld_f4o(xb0,ci0<<4) : z;
    float4 xA1 = v01 ? ld_f4o(xb0,ci1<<4) : z;
    float4 xB0 = v10 ? ld_f4o(xb1,cj0<<4) : z;
    float4 xB1 = v11 ? ld_f4o(xb1,cj1<<4) : z;
    u32 wA0 = ld_u32o(hp,(sA0<<7)+coloff);
    u32 wA1 = ld_u32o(hp,(sA1<<7)+coloff);
    u32 wB0 = ld_u32o(hp,(sB0<<7)+coloff);
    u32 wB1 = ld_u32o(hp,(sB1<<7)+coloff);
    acc2x4(aA, dA01, dA23, xA0, wA0);
    acc2x4(aA, dA01, dA23, xA1, wA1);
    acc2x4(aB, dB01, dB23, xB0, wB0);
    acc2x4(aB, dB01, dB23, xB1, wB1);
    k0+=4; k1+=4;
  }
  // cross-half reduction
  #pragma unroll
  for (int u=0;u<4;u++){
    aA[u].x += __shfl_xor(aA[u].x,32,64); aA[u].y += __shfl_xor(aA[u].y,32,64);
    aB[u].x += __shfl_xor(aB[u].x,32,64); aB[u].y += __shfl_xor(aB[u].y,32,64);
  }
  dA01.x += __shfl_xor(dA01.x,32,64); dA01.y += __shfl_xor(dA01.y,32,64);
  dA23.x += __shfl_xor(dA23.x,32,64); dA23.y += __shfl_xor(dA23.y,32,64);
  dB01.x += __shfl_xor(dB01.x,32,64); dB01.y += __shfl_xor(dB01.y,32,64);
  dB23.x += __shfl_xor(dB23.x,32,64); dB23.y += __shfl_xor(dB23.y,32,64);
  if (!half){
    bool hg0 = e0_ > b0_, hg1 = e1_ > b1_;
    float iA[4] = { hg0?1.f/dA01.x:0.f, hg0?1.f/dA01.y:0.f, hg0?1.f/dA23.x:0.f, hg0?1.f/dA23.y:0.f };
    float iB[4] = { hg1?1.f/dB01.x:0.f, hg1?1.f/dB01.y:0.f, hg1?1.f/dB23.x:0.f, hg1?1.f/dB23.y:0.f };
    u32* og0 = (u32*)(aggB + (size_t)n*256);
    u32* og1 = (u32*)(aggB + aggStride + (size_t)n*256);
    #pragma unroll
    for (int h=0;h<4;h++){
      u32 w0 = (u32)f2bf(aA[h].x*iA[h]) | ((u32)f2bf(aA[h].y*iA[h])<<16);
      og0[h*32 + l32] = w0;
      u32 w1 = (u32)f2bf(aB[h].x*iB[h]) | ((u32)f2bf(aB[h].y*iB[h])<<16);
      og1[h*32 + l32] = w1;
    }
  }
}

// ---------- layer-0 head GEMM: ELU(agg@W0_blockdiag + b) mixed -> h1 ----------
// v2: h-loop split across 2 block groups (2 heads each) -> 2x wave parallelism.
__global__ __launch_bounds__(256) void k_head0(
    const u16* __restrict__ aggB, size_t aggStride,
    const u16* __restrict__ W0p, const float* __restrict__ b0,
    const float* __restrict__ wsoft, u16* __restrict__ h1)
{
  int wv = threadIdx.x>>6, ln = threadIdx.x&63;
  int bg = blockIdx.x;
  int hbase = (bg / NGRP)*2;
  int ti = (bg % NGRP)*4 + wv;
  if (ti >= NRT) return;
  int q = ln>>4, c = ln&15;
  int type = (ti < NT0) ? 0 : 1;
  float wg0 = wsoft[type*6 + 0];
  float wg1 = wsoft[type*6 + 1];
  for (int h=hbase; h<hbase+2; h++){
    f32x4 acc[2][4] = {};
    #pragma unroll
    for (int g=0; g<2; g++){
      const u16* Ap = aggB + (size_t)g*aggStride + (size_t)(ti*16 + c)*256 + h*64 + q*8;
      const u16* Bg = W0p + (size_t)g*16384;
      #pragma unroll
      for (int kb=0; kb<2; kb++){
        bf16x8 a = ld_frag(Ap + kb*32);
        #pragma unroll
        for (int ct=0; ct<4; ct++){
          int ctg = h*4 + ct;
          bf16x8 b = ld_frag(Bg + ((size_t)(ctg*2 + kb)*64 + ln)*8);
          acc[g][ct] = __builtin_amdgcn_mfma_f32_16x16x32_bf16(a, b, acc[g][ct], 0,0,0);
        }
      }
    }
    #pragma unroll
    for (int ct=0; ct<4; ct++){
      int colg = h*64 + ct*16 + c;
      float bb0 = b0[colg], bb1 = b0[256 + colg];
      #pragma unroll
      for (int j=0;j<4;j++){
        int row = ti*16 + q*4 + j;
        float o = wg0*elu_f(acc[0][ct][j] + bb0) + wg1*elu_f(acc[1][ct][j] + bb1);
        h1[(size_t)row*256 + colg] = f2bf(o);
      }
    }
  }
}

// ---------- MFMA GEMM (layer 1): 2 row-tiles x 4 col-tiles per wave ------------
template<int K>
__global__ __launch_bounds__(256) void k_gemm4(
    const u16* __restrict__ A,
    const u16* __restrict__ Bp, size_t bpStride,
    const float* __restrict__ al, const float* __restrict__ ar, int alStride,
    u16* __restrict__ feat, size_t featStride,
    float* __restrict__ el, float* __restrict__ er, size_t elStride)
{
  constexpr int KB = K/32;
  int wv = threadIdx.x>>6, ln = threadIdx.x&63;
  int bid = blockIdx.x;
  int g = bid / NGRP2, grp = bid % NGRP2;
  int split = wv, q = ln>>4, c = ln&15;
  const u16* Bpg = Bp + (size_t)g*bpStride;
  const float* alg = al + (size_t)g*alStride;
  const float* arg = ar + (size_t)g*alStride;
  u16* featg = feat + (size_t)g*featStride;
  float* elg = el + (size_t)g*elStride;
  float* erg = er + (size_t)g*elStride;

  f32x4 acc[2][4] = {};
  int  tbase = grp*2;
  bool valid[2];
  const u16* Ap[2];
  #pragma unroll
  for (int rt=0; rt<2; rt++){
    int ti = tbase + rt;
    valid[rt] = (ti < NRT);
    if (!valid[rt]) ti = NRT-1;
    Ap[rt] = A + (size_t)(ti*16 + c)*K + q*8;
  }
  const u16* Bbase = Bpg + ((size_t)(split*4)*KB*64 + ln)*8;

  #pragma unroll 2
  for (int kb=0; kb<KB; kb++){
    bf16x8 b[4], a[2];
    #pragma unroll
    for (int ct=0; ct<4; ct++) b[ct] = ld_frag(Bbase + (size_t)(ct*KB + kb)*64*8);
    #pragma unroll
    for (int rt=0; rt<2; rt++) a[rt] = ld_frag(Ap[rt] + kb*32);
    #pragma unroll
    for (int rt=0; rt<2; rt++)
      #pragma unroll
      for (int ct=0; ct<4; ct++)
        acc[rt][ct] = __builtin_amdgcn_mfma_f32_16x16x32_bf16(a[rt], b[ct], acc[rt][ct], 0,0,0);
  }

  float alv[4], arv[4];
  #pragma unroll
  for (int ct=0;ct<4;ct++){
    int cg = (split*4+ct)*16 + c;
    alv[ct] = alg[cg]; arv[ct] = arg[cg];
  }
  #pragma unroll
  for (int rt=0; rt<2; rt++){
    if (!valid[rt]) continue;
    int row0 = (tbase+rt)*16;
    #pragma unroll
    for (int j=0;j<4;j++){
      float ep=0.f, rp=0.f;
      #pragma unroll
      for (int ct=0;ct<4;ct++){ ep += acc[rt][ct][j]*alv[ct]; rp += acc[rt][ct][j]*arv[ct]; }
      #pragma unroll
      for (int off=8; off; off>>=1){ ep += __shfl_xor(ep,off,16); rp += __shfl_xor(rp,off,16); }
      int row = row0 + q*4 + j;
      if (c==0){ elg[row*4+split]=ep; erg[row*4+split]=rp; }
      #pragma unroll
      for (int ct=0;ct<4;ct++)
        featg[(size_t)row*256 + (split*4+ct)*16 + c] = f2bf(acc[rt][ct][j]);
    }
  }
}

// ---------- fused dual-graph gather aggregation (256 cols, H=4), layer 1 -------
// v5: R2-v3 structure + 32-bit byte-offset addressing on all hot loads.
template<int RES>
__global__ __launch_bounds__(128) void k_aggNF(
    const int* __restrict__ row2, const u16* __restrict__ col2,
    const float* __restrict__ xbuf,
    const u16* __restrict__ feat, size_t featStride,
    const u16* __restrict__ hres, const float* __restrict__ bias,
    const float* __restrict__ wsoft, int l,
    u16* __restrict__ hout)
{
  int wv = threadIdx.x>>6, ln = threadIdx.x&63;
  int n = blockIdx.x*2 + wv;
  int half = ln>>5, l32 = ln&31;
  int hh = l32>>3;                       // head of this lane's 8 cols
  u32 rowoff = (u32)l32<<4;              // byte offset within 512B feat row
  u32 hhb    = (u32)hh<<2;               // byte offset of head in xbuf float4
  int type = (n<NN0)?0:1;
  const char* cl0 = (const char*)col2;
  const char* cl1 = (const char*)(col2 + EE);
  const char* x0p = (const char*)xbuf;                       // float4/edge
  const char* x1p = x0p + (size_t)EE*16;
  const char* fp0 = (const char*)feat;                       // 512B rows
  const char* fp1 = (const char*)(feat + featStride);
  int b0_ = row2[n], e0_ = row2[n+1];
  int b1_ = row2[(NN+1)+n], e1_ = row2[(NN+1)+n+1];
  int n0 = e0_-b0_, n1 = e1_-b1_;
  int mx = n0>n1 ? n0 : n1;
  int iters = (mx+3)>>2;
  f32x2 pA[4] = {}; f32x2 pB[4] = {};
  float denA = 0.f, denB = 0.f;
  int k0 = b0_+half, k1 = b1_+half;
  for (int it=0; it<iters; ++it){
    int i0=k0, i1=k0+2, j0=k1, j1=k1+2;
    bool v00=i0<e0_, v01=i1<e0_, v10=j0<e1_, v11=j1<e1_;
    u32 ci0=v00?(u32)i0:0u, ci1=v01?(u32)i1:0u, cj0=v10?(u32)j0:0u, cj1=v11?(u32)j1:0u;
    u32 sA0=ld_u16o(cl0,ci0<<1), sA1=ld_u16o(cl0,ci1<<1);
    u32 sB0=ld_u16o(cl1,cj0<<1), sB1=ld_u16o(cl1,cj1<<1);
    float xA0 = v00 ? ld_f32o(x0p,(ci0<<4)+hhb) : 0.f;
    float xA1 = v01 ? ld_f32o(x0p,(ci1<<4)+hhb) : 0.f;
    float xB0 = v10 ? ld_f32o(x1p,(cj0<<4)+hhb) : 0.f;
    float xB1 = v11 ? ld_f32o(x1p,(cj1<<4)+hhb) : 0.f;
    uint4 fA0 = ld_u4o(fp0,(sA0<<9)+rowoff);
    uint4 fA1 = ld_u4o(fp0,(sA1<<9)+rowoff);
    uint4 fB0 = ld_u4o(fp1,(sB0<<9)+rowoff);
    uint4 fB1 = ld_u4o(fp1,(sB1<<9)+rowoff);
    acc8pk(pA, denA, xA0, fA0);
    acc8pk(pA, denA, xA1, fA1);
    acc8pk(pB, denB, xB0, fB0);
    acc8pk(pB, denB, xB1, fB1);
    k0+=4; k1+=4;
  }
  // cross-half reduction (lane i and i^32 hold same cols, disjoint edges)
  #pragma unroll
  for (int u=0;u<4;u++){
    pA[u].x += __shfl_xor(pA[u].x,32,64); pA[u].y += __shfl_xor(pA[u].y,32,64);
    pB[u].x += __shfl_xor(pB[u].x,32,64); pB[u].y += __shfl_xor(pB[u].y,32,64);
  }
  denA += __shfl_xor(denA,32,64);
  denB += __shfl_xor(denB,32,64);
  if (!half){
    float accA[8], accB[8];
    #pragma unroll
    for (int u=0;u<4;u++){
      accA[2*u]=pA[u].x; accA[2*u+1]=pA[u].y;
      accB[2*u]=pB[u].x; accB[2*u+1]=pB[u].y;
    }
    float inv0 = (e0_>b0_) ? 1.0f/denA : 0.f;
    float inv1 = (e1_>b1_) ? 1.0f/denB : 0.f;
    const float4* bp0 = (const float4*)bias;
    const float4* bp1 = (const float4*)(bias + 256);
    float4 bva = bp0[l32*2], bvb = bp0[l32*2+1];
    float4 bwa = bp1[l32*2], bwb = bp1[l32*2+1];
    float bb0[8] = {bva.x,bva.y,bva.z,bva.w,bvb.x,bvb.y,bvb.z,bvb.w};
    float bb1[8] = {bwa.x,bwa.y,bwa.z,bwa.w,bwb.x,bwb.y,bwb.z,bwb.w};
    float w0 = wsoft[type*6 + l*2 + 0];
    float w1 = wsoft[type*6 + l*2 + 1];
    float r[8] = {0.f,0.f,0.f,0.f,0.f,0.f,0.f,0.f};
    if (RES){
      uint4 rr = ((const uint4*)hres)[(size_t)n*32 + l32];
      r[0]=lo16(rr.x); r[1]=hi16(rr.x); r[2]=lo16(rr.y); r[3]=hi16(rr.y);
      r[4]=lo16(rr.z); r[5]=hi16(rr.z); r[6]=lo16(rr.w); r[7]=hi16(rr.w);
    }
    u16 ov[8];
    #pragma unroll
    for (int j=0;j<8;j++){
      float c = accA[j]*inv0 + bb0[j] + r[j];
      float e = accB[j]*inv1 + bb1[j] + r[j];
      ov[j] = f2bf(w0*elu_f(c) + w1*elu_f(e));
    }
    uint4 o;
    o.x = (u32)ov[0] | ((u32)ov[1]<<16);
    o.y = (u32)ov[2] | ((u32)ov[3]<<16);
    o.z = (u32)ov[4] | ((u32)ov[5]<<16);
    o.w = (u32)ov[6] | ((u32)ov[7]<<16);
    ((uint4*)hout)[(size_t)n*32 + l32] = o;
  }
}

// ---------- layer-2 MFMA: A(N,256) @ [W2_0|res2_0|W2_1|res2_1](256,64) ----------
__global__ __launch_bounds__(256) void k_gemm2(
    const u16* __restrict__ A, const u16* __restrict__ Bp,
    const float* __restrict__ al2, const float* __restrict__ ar2,
    u16* __restrict__ feat16, float* __restrict__ resb,
    float* __restrict__ el2, float* __restrict__ er2)
{
  int wv = threadIdx.x>>6, ln = threadIdx.x&63;
  int wt = blockIdx.x*4 + wv;
  if (wt >= NRT) return;
  int row0 = wt*16;
  int q = ln>>4, c = ln&15;
  f32x4 acc[4] = {};
  const u16* Ap = A + (size_t)(row0 + c)*256 + q*8;
  #pragma unroll
  for (int kb=0; kb<8; kb++){
    bf16x8 a = ld_frag(Ap + kb*32);
    #pragma unroll
    for (int t=0;t<4;t++){
      bf16x8 b = ld_frag(Bp + ((size_t)(t*8 + kb)*64 + ln)*8);
      acc[t] = __builtin_amdgcn_mfma_f32_16x16x32_bf16(a, b, acc[t], 0,0,0);
    }
  }
  #pragma unroll
  for (int i=0;i<2;i++){
    float alv = al2[i*16+c], arv = ar2[i*16+c];
    #pragma unroll
    for (int j=0;j<4;j++){
      float ep = acc[2*i][j]*alv, rp = acc[2*i][j]*arv;
      #pragma unroll
      for (int off=8; off; off>>=1){ ep += __shfl_xor(ep,off,16); rp += __shfl_xor(rp,off,16); }
      if (c==0){
        int row = row0 + q*4 + j;
        el2[(size_t)i*NN + row] = ep; er2[(size_t)i*NN + row] = rp;
      }
    }
    #pragma unroll
    for (int j=0;j<4;j++){
      int row = row0 + q*4 + j;
      feat16[(size_t)i*NN*16 + (size_t)row*16 + c] = f2bf(acc[2*i][j]);
      resb  [(size_t)i*NN*16 + (size_t)row*16 + c] = acc[2*i+1][j];
    }
  }
}

// ---------- layer-2 dual-graph aggregation + inline alpha + final mix ----------
// v2: 32-bit byte-offset addressing on the per-edge gathers.
__global__ __launch_bounds__(256) void k_agg2D(
    const int* __restrict__ row2, const u16* __restrict__ col2,
    const float* __restrict__ el2, const float* __restrict__ er2,
    const u16* __restrict__ feat16, const float* __restrict__ resb,
    const float* __restrict__ b2, const float* __restrict__ wsoft,
    float* __restrict__ out)
{
  int t = threadIdx.x;
  int nl = t>>4, j = t&15;
  int n = blockIdx.x*16 + nl;
  u32 jb = (u32)j<<1;
  int type = (n<NN0)?0:1;
  float o = 0.f;
  #pragma unroll
  for (int i=0;i<2;i++){
    const int* rw = row2 + (size_t)i*(NN+1);
    const char* cl = (const char*)(col2 + (size_t)i*EE);
    const char* elg = (const char*)(el2 + (size_t)i*NN);
    float ern = er2[(size_t)i*NN + n];
    const char* f = (const char*)(feat16 + (size_t)i*NN*16);
    int beg = rw[n], end = rw[n+1];
    float den = 0.f, acc = 0.f;
    int k = beg;
    for (; k+4<=end; k+=4){
      u32 kb = (u32)k<<1;
      u32 s0=ld_u16o(cl,kb), s1=ld_u16o(cl,kb+2), s2=ld_u16o(cl,kb+4), s3=ld_u16o(cl,kb+6);
      float x0 = __expf(lrelu(ld_f32o(elg,s0<<2) + ern));
      float x1 = __expf(lrelu(ld_f32o(elg,s1<<2) + ern));
      float x2 = __expf(lrelu(ld_f32o(elg,s2<<2) + ern));
      float x3 = __expf(lrelu(ld_f32o(elg,s3<<2) + ern));
      float v0 = bf2f((u16)ld_u16o(f,(s0<<5)+jb));
      float v1 = bf2f((u16)ld_u16o(f,(s1<<5)+jb));
      float v2 = bf2f((u16)ld_u16o(f,(s2<<5)+jb));
      float v3 = bf2f((u16)ld_u16o(f,(s3<<5)+jb));
      den += (x0+x1) + (x2+x3);
      acc += x0*v0 + x1*v1 + x2*v2 + x3*v3;
    }
    for (; k<end; k++){
      u32 s = ld_u16o(cl,(u32)k<<1);
      float x = __expf(lrelu(ld_f32o(elg,s<<2) + ern));
      den += x;
      acc = fmaf(x, bf2f((u16)ld_u16o(f,(s<<5)+jb)), acc);
    }
    float inv = (end>beg) ? 1.0f/den : 0.f;
    float oi = acc*inv + b2[i*16+j] + resb[(size_t)i*NN*16 + (size_t)n*16 + j];
    o += oi * wsoft[type*6 + 4 + i];
  }
  out[(size_t)n*16 + j] = o;
}

extern "C" void kernel_launch(void* const* d_in, const int* in_sizes, int n_in,
                              void* d_out, int out_size, void* d_ws, size_t ws_size,
                              hipStream_t stream)
{
  const float* features0 = (const float*)d_in[0];
  const float* features1 = (const float*)d_in[1];
  const float* fc_w0 = (const float*)d_in[2];
  const float* fc_b0 = (const float*)d_in[3];
  const float* fc_w1 = (const float*)d_in[4];
  const float* fc_b1 = (const float*)d_in[5];
  const float* mix_w = (const float*)d_in[6];
  const float* W0  = (const float*)d_in[7];
  const float* al0 = (const float*)d_in[8];
  const float* ar0 = (const float*)d_in[9];
  const float* b0  = (const float*)d_in[10];
  const float* W1  = (const float*)d_in[11];
  const float* al1 = (const float*)d_in[12];
  const float* ar1 = (const float*)d_in[13];
  const float* b1  = (const float*)d_in[14];
  const float* W2  = (const float*)d_in[15];
  const float* al2 = (const float*)d_in[16];
  const float* ar2 = (const float*)d_in[17];
  const float* b2  = (const float*)d_in[18];
  const float* res2= (const float*)d_in[19];
  const int* src[2] = {(const int*)d_in[20], (const int*)d_in[22]};
  const int* dst[2] = {(const int*)d_in[21], (const int*)d_in[23]};
  (void)in_sizes; (void)n_in; (void)out_size; (void)ws_size;

  char* ws = (char*)d_ws;
  size_t off = 0;
  auto alloc = [&](size_t bytes)->char*{
    char* p = ws + off; off += (bytes + 255) & ~(size_t)255; return p;
  };
  float* wsoft = (float*)alloc(64*4);
  u16*   W0p   = (u16*)  alloc((size_t)2*64*256*2);
  u16*   W1p   = (u16*)  alloc((size_t)2*256*256*2);
  u16*   W2p   = (u16*)  alloc((size_t)256*64*2);
  u16*   Fp    = (u16*)  alloc((size_t)2*128*64*2);
  u16*   V2p   = (u16*)  alloc((size_t)2*128*16*2);
  float* bV    = (float*)alloc((size_t)32*4);
  int*   row2  = (int*)  alloc((size_t)2*(NN+1)*4);
  u16*   col2  = (u16*)  alloc((size_t)2*EE*2);
  u16*   dstOf = (u16*)  alloc((size_t)2*EE*2);
  int*   zeros = (int*)  alloc((size_t)4*NN*4);       // cnt2 + fill2, zeroed in prep
  int*   cnt2  = zeros;
  int*   fill2 = zeros + 2*NN;
  int*   bsum  = (int*)alloc((size_t)2*NB_SCAN*4);
  u16*   h0    = (u16*)alloc((size_t)NN*64*2);
  u16*   h1    = (u16*)alloc((size_t)NN*256*2);
  u16*   h2    = (u16*)alloc((size_t)NN*256*2);
  float* elA   = (float*)alloc((size_t)2*NN*4*4);
  float* erA   = (float*)alloc((size_t)2*NN*4*4);
  float* xbuf  = (float*)alloc((size_t)2*EE*4*4);     // 12.8 MB, reused L0/L1
  // region D (51.2 MB): layer-0 aggB -> layer-1 featD -> layer-2 outputs
  size_t featStride = (size_t)NN*256;                 // u16 elements per graph
  size_t off_D = off;
  u16* regionD = (u16*)alloc(2*featStride*2);
  u16* aggB  = regionD;
  u16* featD = regionD;
  u16*   feat16 = (u16*)(ws + off_D);                          // 2*NN*16 u16 (3.2 MB)
  float* resb   = (float*)(ws + off_D + (size_t)2*NN*16*2);    // 2*NN*16 f32
  float* el2    = resb + (size_t)2*NN*16;
  float* er2    = el2  + (size_t)2*NN;

  // 1. prep ∪ prep2 (one dispatch)
  k_prepAll<<<132,256,0,stream>>>(mix_w, wsoft, W0, W0p, W1, W1p, W2, res2, W2p,
                                  fc_w0, fc_w1, Fp, al0, ar0, fc_b0, fc_b1,
                                  V2p, bV, zeros);

  // 2. input projection (MFMA, + fused layer-0 el/er) ∪ edge count (one dispatch)
  k_inpcnt<<<NGRP + 2*NB_E,256,0,stream>>>(features0, features1, Fp, fc_b0, fc_b1,
                                           V2p, bV, h0, elA, erA,
                                           dst[0], dst[1], cnt2);

  // 3. CSR scan + scatter
  {
    dim3 gS(NB_SCAN, 2), gEb(NB_E, 2);
    k_scan1  <<<gS,1024,0,stream>>>(cnt2, row2, bsum);
    k_scan3  <<<gS,1024,0,stream>>>(row2, bsum);
    k_scatter2<<<gEb,256,0,stream>>>(src[0], dst[0], src[1], dst[1], row2, fill2, col2, dstOf);
  }

  dim3 gE(NB_E, 2);

  // 4. layer 0: alpha, interleaved dual-graph aggregate (2-wave blocks), head GEMM
  k_alpha4<<<gE,256,0,stream>>>(col2, dstOf, elA, erA, (size_t)NN*4, xbuf);
  k_agg0 <<<NN/2,128,0,stream>>>(row2, col2, xbuf, h0, aggB, featStride);
  k_head0<<<2*NGRP,256,0,stream>>>(aggB, featStride, W0p, b0, wsoft, h1);

  // 5. layer 1: feat = h1 @ W1 (MFMA), alpha, fused aggregation (2-wave blocks)
  k_gemm4<256><<<2*NGRP2,256,0,stream>>>(h1, W1p, (size_t)256*256, al1, ar1, 256,
                                         featD, featStride, elA, erA, (size_t)NN*4);
  k_alpha4<<<gE,256,0,stream>>>(col2, dstOf, elA, erA, (size_t)NN*4, xbuf);
  k_aggNF<1><<<NN/2,128,0,stream>>>(row2, col2, xbuf, featD, featStride,
                                    h1, b1, wsoft, 1, h2);

  // 6. layer 2 (both graphs fused; alpha inline in agg2D; feat16 bf16)
  k_gemm2<<<NGRP,256,0,stream>>>(h2, W2p, al2, ar2, feat16, resb, el2, er2);
  k_agg2D<<<NN/16,256,0,stream>>>(row2, col2, el2, er2, feat16, resb, b2, wsoft, (float*)d_out);
}